// Round 10
// baseline (1015.701 us; speedup 1.0000x reference)
//
#include <hip/hip_runtime.h>
#include <hip/hip_bf16.h>
#include <math.h>

#define INDIM 16
#define EMBD 32
#define UDIM 64
#define HIDD 128
#define HEADS 4
#define LAYERS 3
#define MPAD 50048  // 391 * 128
#define NSLICE 32   // bn-sum stripes (atomic contention reduction)

typedef short v8s __attribute__((ext_vector_type(8)));
typedef float v4f __attribute__((ext_vector_type(4)));

__device__ __forceinline__ float lrelu(float x) { return x > 0.f ? x : 0.2f * x; }
__device__ __forceinline__ float bf2f(unsigned int bits16) {
    unsigned int u = bits16 << 16;
    return __builtin_bit_cast(float, u);
}
__device__ __forceinline__ unsigned short f2bf(float f) {
    unsigned int u = __builtin_bit_cast(unsigned int, f);
    unsigned int lsb = (u >> 16) & 1;
    u += 0x7fff + lsb;  // round to nearest even
    return (unsigned short)(u >> 16);
}

// ---------------- encoder features: u = [emb, x@Wf^T + bf] in bf16 ----------------
__global__ __launch_bounds__(256) void k_enc(const float* __restrict__ x,
                                             const float* __restrict__ emb,
                                             const float* __restrict__ Wf,
                                             const float* __restrict__ bf,
                                             unsigned short* __restrict__ u, int n) {
    int i = blockIdx.x * 256 + threadIdx.x;
    if (i >= n * EMBD) return;
    int node = i >> 5, j = i & 31;
    const float* xr = x + (size_t)node * INDIM;
    const float* wr = Wf + (size_t)j * INDIM;
    float s = bf[j];
#pragma unroll
    for (int k = 0; k < INDIM; k++) s += xr[k] * wr[k];
    u[(size_t)node * UDIM + EMBD + j] = f2bf(s);
    u[(size_t)node * UDIM + j] = f2bf(emb[(size_t)node * EMBD + j]);
}

// ---------------- weight precompute ----------------
__global__ __launch_bounds__(256) void k_prep_v(const float* __restrict__ Wl,
                                                unsigned short* __restrict__ Vb) {
    int i = blockIdx.x * 256 + threadIdx.x;
    if (i >= LAYERS * HIDD * 512) return;
    int l = i >> 16;
    int rem = i & 65535;
    int c = rem >> 9;
    int f = rem & 511;
    int h = f >> 7, k = f & 127;
    Vb[i] = f2bf(Wl[(size_t)l * 512 * HIDD + (size_t)(h * HIDD + c) * HIDD + k]);
}

// ws[l][h][k] = sum_c a_s[l,h,c] * Wl[l][h*128+c][k]   (and wd for a_dst)
__global__ __launch_bounds__(256) void k_prep_a(const float* __restrict__ Wl,
                                                const float* __restrict__ a_s,
                                                const float* __restrict__ a_d,
                                                float* __restrict__ ws, float* __restrict__ wd) {
    int i = blockIdx.x * 256 + threadIdx.x;
    if (i >= LAYERS * HEADS * HIDD) return;
    int l = i >> 9, h = (i >> 7) & 3, k = i & 127;
    const float* W = Wl + (size_t)l * 512 * HIDD;
    const float* as = a_s + l * 512 + h * HIDD;
    const float* ad = a_d + l * 512 + h * HIDD;
    float ss = 0.f, sd = 0.f;
    for (int c = 0; c < HIDD; c++) {
        float w = W[(size_t)(h * HIDD + c) * HIDD + k];
        ss += as[c] * w;
        sd += ad[c] * w;
    }
    ws[i] = ss;
    wd[i] = sd;
}

__global__ __launch_bounds__(256) void k_prep_wc(const float* __restrict__ Wc,
                                                 unsigned short* __restrict__ Wcb) {
    int i = blockIdx.x * 256 + threadIdx.x;
    if (i < HIDD * UDIM) Wcb[i] = f2bf(Wc[i]);
}

// ---------------- encoder MFMA GEMM: O(M,128) = A(M,64) @ B(128,64)^T + bias, relu ----------------
__global__ __launch_bounds__(256) void k_gemm_enc(const unsigned short* __restrict__ A,
                                                  const unsigned short* __restrict__ B,
                                                  const float* __restrict__ bias,
                                                  float* __restrict__ O,
                                                  unsigned short* __restrict__ Ob, int M) {
    const int K = UDIM;
    int tid = threadIdx.x;
    int lane = tid & 63, wid = tid >> 6;
    int wm = wid >> 1, wn = wid & 1;
    int bm = blockIdx.x * 128;
    int lr = lane & 15, lk = lane >> 4;
    v4f acc[4][4] = {};
    const unsigned short* Abase = A + (size_t)(bm + wm * 64 + lr) * K + lk * 8;
    const unsigned short* Bbase = B + (size_t)(wn * 64 + lr) * K + lk * 8;
#pragma unroll
    for (int kk = 0; kk < K / 32; kk++) {
        v8s a[4], b[4];
#pragma unroll
        for (int f = 0; f < 4; f++) {
            a[f] = *(const v8s*)(Abase + (size_t)(f * 16) * K + kk * 32);
            b[f] = *(const v8s*)(Bbase + (size_t)(f * 16) * K + kk * 32);
        }
#pragma unroll
        for (int i = 0; i < 4; i++)
#pragma unroll
            for (int j = 0; j < 4; j++)
                acc[i][j] = __builtin_amdgcn_mfma_f32_16x16x32_bf16(a[i], b[j], acc[i][j], 0, 0, 0);
    }
#pragma unroll
    for (int i = 0; i < 4; i++) {
#pragma unroll
        for (int r = 0; r < 4; r++) {
            int row = bm + wm * 64 + i * 16 + lk * 4 + r;
            if (row >= M) continue;
#pragma unroll
            for (int j = 0; j < 4; j++) {
                int col = wn * 64 + j * 16 + lr;
                float v = fmaxf(acc[i][j][r] + bias[col], 0.f);
                O[(size_t)row * HIDD + col] = v;
                Ob[(size_t)row * HIDD + col] = f2bf(v);
            }
        }
    }
}

// ---------------- CSR build ----------------
__global__ __launch_bounds__(256) void k_deg(const int* __restrict__ ei, int* __restrict__ deg,
                                             int E, int tot) {
    int e = blockIdx.x * 256 + threadIdx.x;
    if (e >= tot) return;
    int dst = (e < E) ? ei[E + e] : (e - E);
    atomicAdd(&deg[dst], 1);
}

__global__ __launch_bounds__(256) void k_scan1(const int* __restrict__ deg,
                                               int* __restrict__ rowptr,
                                               int* __restrict__ partials, int n) {
    int tid = threadIdx.x;
    int i = blockIdx.x * 256 + tid;
    int v = (i < n) ? deg[i] : 0;
    __shared__ int sm[256];
    sm[tid] = v;
    __syncthreads();
    for (int off = 1; off < 256; off <<= 1) {
        int t = (tid >= off) ? sm[tid - off] : 0;
        __syncthreads();
        sm[tid] += t;
        __syncthreads();
    }
    if (i < n) rowptr[i] = sm[tid] - v;  // exclusive within block
    if (tid == 255) partials[blockIdx.x] = sm[255];
}

__global__ __launch_bounds__(256) void k_scan2(int* __restrict__ partials, int nb) {
    int tid = threadIdx.x;
    int v = (tid < nb) ? partials[tid] : 0;
    __shared__ int sm[256];
    sm[tid] = v;
    __syncthreads();
    for (int off = 1; off < 256; off <<= 1) {
        int t = (tid >= off) ? sm[tid - off] : 0;
        __syncthreads();
        sm[tid] += t;
        __syncthreads();
    }
    if (tid < nb) partials[tid] = sm[tid] - v;  // exclusive
}

__global__ __launch_bounds__(256) void k_scan3(const int* __restrict__ deg,
                                               const int* __restrict__ partials,
                                               int* __restrict__ rowptr,
                                               int* __restrict__ cursor, int n) {
    int i = blockIdx.x * 256 + threadIdx.x;
    if (i >= n) return;
    int r = rowptr[i] + partials[blockIdx.x];
    rowptr[i] = r;
    cursor[i] = r;
    if (i == n - 1) rowptr[n] = r + deg[i];
}

__global__ __launch_bounds__(256) void k_scatter(const int* __restrict__ ei, int* __restrict__ cursor,
                                                 int* __restrict__ csr_src, int E, int tot) {
    int e = blockIdx.x * 256 + threadIdx.x;
    if (e >= tot) return;
    int src = (e < E) ? ei[e] : (e - E);
    int dst = (e < E) ? ei[E + e] : (e - E);
    int pos = atomicAdd(&cursor[dst], 1);
    csr_src[pos] = src;
}

// ---------------- layer-0 attention logits from fp32 h ----------------
__global__ __launch_bounds__(256) void k_al0(const float* __restrict__ h,
                                             const float* __restrict__ ws,
                                             const float* __restrict__ wd,
                                             float* __restrict__ al_s, float* __restrict__ al_d,
                                             int n) {
    int wid = threadIdx.x >> 6, lane = threadIdx.x & 63;
    int node = blockIdx.x * 4 + wid;
    if (node >= n) return;
    float2 v = *(const float2*)(h + (size_t)node * HIDD + 2 * lane);
    float s[8];
#pragma unroll
    for (int hh = 0; hh < 4; hh++) {
        float2 w1 = *(const float2*)(ws + hh * HIDD + 2 * lane);
        float2 w2 = *(const float2*)(wd + hh * HIDD + 2 * lane);
        s[hh] = v.x * w1.x + v.y * w1.y;
        s[4 + hh] = v.x * w2.x + v.y * w2.y;
    }
#pragma unroll
    for (int o = 32; o; o >>= 1)
#pragma unroll
        for (int q = 0; q < 8; q++) s[q] += __shfl_xor(s[q], o);
    if (lane == 0) {
        *(float4*)(al_s + (size_t)node * 4) = make_float4(s[0], s[1], s[2], s[3]);
        *(float4*)(al_d + (size_t)node * 4) = make_float4(s[4], s[5], s[6], s[7]);
    }
}

// ---------------- fused layer: 4 waves / 4 nodes per block (small barrier domain) ----------
// Wave-per-node softmax + LDS-staged pipelined gather; Phase B: 16x16 MFMA where A rows 4..15
// read a shared zero row (rmin trick). 8 blocks/CU resident -> 8 independent barrier domains.
__global__ __launch_bounds__(256) void k_layer(const int* __restrict__ rowptr,
                                               const int* __restrict__ csr_src,
                                               const float* __restrict__ al_s,
                                               const float* __restrict__ al_d,
                                               const unsigned short* __restrict__ hb,
                                               const unsigned short* __restrict__ Vb,
                                               float* __restrict__ agg,
                                               float* __restrict__ bns, int n) {
    __shared__ unsigned int Gw[5 * 256];  // rows 0-3 = nodes, row 4 = zeros (A-pad)
    __shared__ float s1[128], s2[128];
    __shared__ int Ssrc[4][64];
    __shared__ float Sal[4][4][64];
    int tid = threadIdx.x, lane = tid & 63, w = tid >> 6;
    if (tid < 128) { s1[tid] = 0.f; s2[tid] = 0.f; }
    Gw[4 * 256 + tid] = 0;  // zero row
    int node0 = blockIdx.x * 4;
    int node = node0 + w;
    const float4* als4 = (const float4*)al_s;
    const unsigned int* h2 = (const unsigned int*)hb;
    int sw = w << 2;

    if (node < n) {
        int start = rowptr[node], end = rowptr[node + 1];
        int deg = end - start;
        float4 ad = ((const float4*)al_d)[node];
        if (deg <= 64) {
            // ---- softmax: lane = edge ----
            bool act = lane < deg;
            int src_l = act ? csr_src[start + lane] : 0;
            float e0 = -3.0e38f, e1 = -3.0e38f, e2 = -3.0e38f, e3 = -3.0e38f;
            if (act) {
                float4 as = als4[src_l];
                e0 = lrelu(as.x + ad.x);
                e1 = lrelu(as.y + ad.y);
                e2 = lrelu(as.z + ad.z);
                e3 = lrelu(as.w + ad.w);
            }
            int span = 1;
            while (span < deg) span <<= 1;
            float m0 = e0, m1 = e1, m2 = e2, m3 = e3;
            for (int o = 1; o < span; o <<= 1) {
                m0 = fmaxf(m0, __shfl_xor(m0, o));
                m1 = fmaxf(m1, __shfl_xor(m1, o));
                m2 = fmaxf(m2, __shfl_xor(m2, o));
                m3 = fmaxf(m3, __shfl_xor(m3, o));
            }
            float p0 = act ? expf(e0 - m0) : 0.f;
            float p1 = act ? expf(e1 - m1) : 0.f;
            float p2 = act ? expf(e2 - m2) : 0.f;
            float p3 = act ? expf(e3 - m3) : 0.f;
            float t0 = p0, t1 = p1, t2 = p2, t3 = p3;
            for (int o = 1; o < span; o <<= 1) {
                t0 += __shfl_xor(t0, o);
                t1 += __shfl_xor(t1, o);
                t2 += __shfl_xor(t2, o);
                t3 += __shfl_xor(t3, o);
            }
            // stage src + alpha to wave-private LDS (inactive lanes: src=0, alpha=0)
            Ssrc[w][lane] = src_l;
            Sal[w][0][lane] = p0 / (t0 + 1e-16f);
            Sal[w][1][lane] = p1 / (t1 + 1e-16f);
            Sal[w][2][lane] = p2 / (t2 + 1e-16f);
            Sal[w][3][lane] = p3 / (t3 + 1e-16f);

            // ---- pipelined gather: 4 edges per iteration, uniform LDS reads ----
            float acc[4][2] = {};
            for (int j0 = 0; j0 < deg; j0 += 4) {
                int4 s4 = *(const int4*)&Ssrc[w][j0];
                float4 af0 = *(const float4*)&Sal[w][0][j0];
                float4 af1 = *(const float4*)&Sal[w][1][j0];
                float4 af2 = *(const float4*)&Sal[w][2][j0];
                float4 af3 = *(const float4*)&Sal[w][3][j0];
                unsigned int u0 = h2[(size_t)s4.x * 64 + lane];
                unsigned int u1 = h2[(size_t)s4.y * 64 + lane];
                unsigned int u2 = h2[(size_t)s4.z * 64 + lane];
                unsigned int u3 = h2[(size_t)s4.w * 64 + lane];
                float x0, x1;
                x0 = bf2f(u0 & 0xffff); x1 = bf2f(u0 >> 16);
                acc[0][0] += af0.x * x0; acc[0][1] += af0.x * x1;
                acc[1][0] += af1.x * x0; acc[1][1] += af1.x * x1;
                acc[2][0] += af2.x * x0; acc[2][1] += af2.x * x1;
                acc[3][0] += af3.x * x0; acc[3][1] += af3.x * x1;
                x0 = bf2f(u1 & 0xffff); x1 = bf2f(u1 >> 16);
                acc[0][0] += af0.y * x0; acc[0][1] += af0.y * x1;
                acc[1][0] += af1.y * x0; acc[1][1] += af1.y * x1;
                acc[2][0] += af2.y * x0; acc[2][1] += af2.y * x1;
                acc[3][0] += af3.y * x0; acc[3][1] += af3.y * x1;
                x0 = bf2f(u2 & 0xffff); x1 = bf2f(u2 >> 16);
                acc[0][0] += af0.z * x0; acc[0][1] += af0.z * x1;
                acc[1][0] += af1.z * x0; acc[1][1] += af1.z * x1;
                acc[2][0] += af2.z * x0; acc[2][1] += af2.z * x1;
                acc[3][0] += af3.z * x0; acc[3][1] += af3.z * x1;
                x0 = bf2f(u3 & 0xffff); x1 = bf2f(u3 >> 16);
                acc[0][0] += af0.w * x0; acc[0][1] += af0.w * x1;
                acc[1][0] += af1.w * x0; acc[1][1] += af1.w * x1;
                acc[2][0] += af2.w * x0; acc[2][1] += af2.w * x1;
                acc[3][0] += af3.w * x0; acc[3][1] += af3.w * x1;
            }
#pragma unroll
            for (int hh = 0; hh < 4; hh++) {
                unsigned int p = (unsigned int)f2bf(acc[hh][0]) |
                                 ((unsigned int)f2bf(acc[hh][1]) << 16);
                Gw[w * 256 + ((hh * 64 + lane) ^ sw)] = p;
            }
        } else {
            // ---- rare fallback: serial-broadcast gather ----
            float m0 = -3.0e38f, m1 = -3.0e38f, m2 = -3.0e38f, m3 = -3.0e38f;
            for (int j = start + lane; j < end; j += 64) {
                float4 as = als4[csr_src[j]];
                m0 = fmaxf(m0, lrelu(as.x + ad.x));
                m1 = fmaxf(m1, lrelu(as.y + ad.y));
                m2 = fmaxf(m2, lrelu(as.z + ad.z));
                m3 = fmaxf(m3, lrelu(as.w + ad.w));
            }
#pragma unroll
            for (int o = 32; o; o >>= 1) {
                m0 = fmaxf(m0, __shfl_xor(m0, o));
                m1 = fmaxf(m1, __shfl_xor(m1, o));
                m2 = fmaxf(m2, __shfl_xor(m2, o));
                m3 = fmaxf(m3, __shfl_xor(m3, o));
            }
            float t0 = 0.f, t1 = 0.f, t2 = 0.f, t3 = 0.f;
            for (int j = start + lane; j < end; j += 64) {
                float4 as = als4[csr_src[j]];
                t0 += expf(lrelu(as.x + ad.x) - m0);
                t1 += expf(lrelu(as.y + ad.y) - m1);
                t2 += expf(lrelu(as.z + ad.z) - m2);
                t3 += expf(lrelu(as.w + ad.w) - m3);
            }
#pragma unroll
            for (int o = 32; o; o >>= 1) {
                t0 += __shfl_xor(t0, o);
                t1 += __shfl_xor(t1, o);
                t2 += __shfl_xor(t2, o);
                t3 += __shfl_xor(t3, o);
            }
            float i0 = 1.f / (t0 + 1e-16f), i1 = 1.f / (t1 + 1e-16f);
            float i2 = 1.f / (t2 + 1e-16f), i3 = 1.f / (t3 + 1e-16f);
            float acc[4][2] = {};
            for (int base = start; base < end; base += 64) {
                int cnt = min(64, end - base);
                bool act2 = lane < cnt;
                int src_l = act2 ? csr_src[base + lane] : 0;
                float a0 = 0.f, a1 = 0.f, a2 = 0.f, a3 = 0.f;
                if (act2) {
                    float4 as = als4[src_l];
                    a0 = expf(lrelu(as.x + ad.x) - m0) * i0;
                    a1 = expf(lrelu(as.y + ad.y) - m1) * i1;
                    a2 = expf(lrelu(as.z + ad.z) - m2) * i2;
                    a3 = expf(lrelu(as.w + ad.w) - m3) * i3;
                }
                for (int jj = 0; jj < cnt; jj++) {
                    int sj = __shfl(src_l, jj);
                    float b0 = __shfl(a0, jj), b1 = __shfl(a1, jj);
                    float b2 = __shfl(a2, jj), b3 = __shfl(a3, jj);
                    unsigned int uu = h2[(size_t)sj * 64 + lane];
                    float x0 = bf2f(uu & 0xffff), x1 = bf2f(uu >> 16);
                    acc[0][0] += b0 * x0; acc[0][1] += b0 * x1;
                    acc[1][0] += b1 * x0; acc[1][1] += b1 * x1;
                    acc[2][0] += b2 * x0; acc[2][1] += b2 * x1;
                    acc[3][0] += b3 * x0; acc[3][1] += b3 * x1;
                }
            }
#pragma unroll
            for (int hh = 0; hh < 4; hh++) {
                unsigned int p = (unsigned int)f2bf(acc[hh][0]) |
                                 ((unsigned int)f2bf(acc[hh][1]) << 16);
                Gw[w * 256 + ((hh * 64 + lane) ^ sw)] = p;
            }
        }
    } else {
        // pad rows: zero
#pragma unroll
        for (int hh = 0; hh < 4; hh++) Gw[w * 256 + ((hh * 64 + lane) ^ sw)] = 0;
    }
    __syncthreads();

    // ---- Phase B: agg(4x128) = G(4x512) @ Vb(128x512)^T; wave w -> cols [w*32, w*32+32)
    // A-fragment rows: lr<4 real rows, lr>=4 -> shared zero row 4.
    {
        int lr = lane & 15, lk = lane >> 4;
        int rmin = min(lr, 4);
        int swr = (rmin & 3) << 2;
        const unsigned int* Arow = &Gw[rmin * 256];
        v4f a2[2] = {{}, {}};
        const unsigned short* Bb0 = Vb + (size_t)(w * 32 + lr) * 512 + lk * 8;
        const unsigned short* Bb1 = Bb0 + (size_t)16 * 512;
#pragma unroll
        for (int kk = 0; kk < 16; kk++) {
            v8s a = *(const v8s*)(&Arow[(kk * 16 + lk * 4) ^ swr]);
            v8s b0 = *(const v8s*)(Bb0 + kk * 32);
            v8s b1 = *(const v8s*)(Bb1 + kk * 32);
            a2[0] = __builtin_amdgcn_mfma_f32_16x16x32_bf16(a, b0, a2[0], 0, 0, 0);
            a2[1] = __builtin_amdgcn_mfma_f32_16x16x32_bf16(a, b1, a2[1], 0, 0, 0);
        }
        if (lk == 0) {  // output rows 0..3 = the 4 nodes
#pragma unroll
            for (int j = 0; j < 2; j++) {
                int col = w * 32 + j * 16 + lr;
                float ls = 0.f, lq = 0.f;
#pragma unroll
                for (int r = 0; r < 4; r++) {
                    int nd = node0 + r;
                    float v = a2[j][r];
                    if (nd < n) {
                        agg[(size_t)nd * HIDD + col] = v;
                        ls += v;
                        lq += v * v;
                    }
                }
                atomicAdd(&s1[col], ls);
                atomicAdd(&s2[col], lq);
            }
        }
    }
    __syncthreads();
    if (tid < 128) {
        float* slice = bns + (size_t)(blockIdx.x & (NSLICE - 1)) * 256;
        atomicAdd(&slice[tid], s1[tid]);
        atomicAdd(&slice[128 + tid], s2[tid]);
    }
}

// ---------------- fused BN finalize+apply + residual + (next-layer al | output head) --------
// scale/shift computed inline from the NSLICE bns stripes (no separate k_bnfin launch).
template <int MODE>
__global__ __launch_bounds__(256) void k_apply(const float* __restrict__ agg,
                                               const float* __restrict__ bns,
                                               const float* __restrict__ gamma,
                                               const float* __restrict__ beta,
                                               float* __restrict__ h,
                                               unsigned short* __restrict__ hb,
                                               const float* __restrict__ ws,
                                               const float* __restrict__ wd,
                                               float* __restrict__ al_s,
                                               float* __restrict__ al_d,
                                               const float* __restrict__ Wout,
                                               const float* __restrict__ bout,
                                               float* __restrict__ out,
                                               float invn, int n) {
    int wid = threadIdx.x >> 6, lane = threadIdx.x & 63;
    int node = blockIdx.x * 4 + wid;
    if (node >= n) return;
    int c0 = 2 * lane, c1 = 2 * lane + 1;
    // inline BN finalize for channels c0,c1
    float s0 = 0.f, q0 = 0.f, s1v = 0.f, q1v = 0.f;
    for (int sl = 0; sl < NSLICE; sl++) {
        float2 a = *(const float2*)(bns + sl * 256 + c0);
        float2 b = *(const float2*)(bns + sl * 256 + 128 + c0);
        s0 += a.x; s1v += a.y;
        q0 += b.x; q1v += b.y;
    }
    float mu0 = s0 * invn, mu1 = s1v * invn;
    float va0 = q0 * invn - mu0 * mu0;
    float va1 = q1v * invn - mu1 * mu1;
    float sc0 = gamma[c0] * rsqrtf(0.0625f * va0 + 1e-5f) * 0.25f;
    float sc1 = gamma[c1] * rsqrtf(0.0625f * va1 + 1e-5f) * 0.25f;
    float sh0 = beta[c0] - mu0 * sc0;
    float sh1 = beta[c1] - mu1 * sc1;

    float2 ag = *(const float2*)(agg + (size_t)node * HIDD + c0);
    float2 ho = *(const float2*)(h + (size_t)node * HIDD + c0);
    float v0 = fmaxf(ag.x * sc0 + sh0, 0.f) + ho.x;
    float v1 = fmaxf(ag.y * sc1 + sh1, 0.f) + ho.y;
    if (MODE == 0) {
        *(float2*)(h + (size_t)node * HIDD + c0) = make_float2(v0, v1);
        ((unsigned int*)hb)[(size_t)node * 64 + lane] =
            (unsigned int)f2bf(v0) | ((unsigned int)f2bf(v1) << 16);
        float s[8];
#pragma unroll
        for (int hh = 0; hh < 4; hh++) {
            float2 w1 = *(const float2*)(ws + hh * HIDD + c0);
            float2 w2 = *(const float2*)(wd + hh * HIDD + c0);
            s[hh] = v0 * w1.x + v1 * w1.y;
            s[4 + hh] = v0 * w2.x + v1 * w2.y;
        }
#pragma unroll
        for (int o = 32; o; o >>= 1)
#pragma unroll
            for (int q = 0; q < 8; q++) s[q] += __shfl_xor(s[q], o);
        if (lane == 0) {
            *(float4*)(al_s + (size_t)node * 4) = make_float4(s[0], s[1], s[2], s[3]);
            *(float4*)(al_d + (size_t)node * 4) = make_float4(s[4], s[5], s[6], s[7]);
        }
    } else {
        float2 w = *(const float2*)(Wout + c0);
        float p = v0 * w.x + v1 * w.y;
#pragma unroll
        for (int o = 32; o; o >>= 1) p += __shfl_xor(p, o);
        if (lane == 0) {
            float v = p + bout[0];
            out[node] = fminf(fmaxf(v, -10.f), 10.f);
        }
    }
}

extern "C" void kernel_launch(void* const* d_in, const int* in_sizes, int n_in,
                              void* d_out, int out_size, void* d_ws, size_t ws_size,
                              hipStream_t stream) {
    const float* x = (const float*)d_in[0];
    const int* ei = (const int*)d_in[1];
    const float* emb = (const float*)d_in[2];
    const float* Wf = (const float*)d_in[3];
    const float* bf = (const float*)d_in[4];
    const float* Wc = (const float*)d_in[5];
    const float* bc = (const float*)d_in[6];
    const float* Wl = (const float*)d_in[7];
    const float* a_src = (const float*)d_in[8];
    const float* a_dst = (const float*)d_in[9];
    // d_in[10] = bl : cancels in BN mean subtraction
    const float* gamma = (const float*)d_in[11];
    const float* beta = (const float*)d_in[12];
    const float* Wout = (const float*)d_in[13];
    const float* bout = (const float*)d_in[14];
    float* out = (float*)d_out;

    int n = in_sizes[0] / INDIM;  // 50000
    int E = in_sizes[1] / 2;      // 400000
    int tot = E + n;
    int NB = (n + 255) / 256;  // scan blocks

    size_t off = 0;
    auto alloc = [&](size_t bytes) {
        void* p = (char*)d_ws + off;
        off = (off + bytes + 255) & ~(size_t)255;
        return p;
    };
    unsigned short* u = (unsigned short*)alloc((size_t)MPAD * UDIM * 2);
    float* h = (float*)alloc((size_t)MPAD * HIDD * 4);
    unsigned short* hb = (unsigned short*)alloc((size_t)MPAD * HIDD * 2);
    float* agg = (float*)alloc((size_t)MPAD * HIDD * 4);
    float* al_s = (float*)alloc((size_t)n * HEADS * 4);
    float* al_d = (float*)alloc((size_t)n * HEADS * 4);
    int* deg = (int*)alloc((size_t)n * 4);
    int* rowptr = (int*)alloc(((size_t)n + 1) * 4);
    int* cursor = (int*)alloc((size_t)n * 4);
    int* csr_src = (int*)alloc((size_t)tot * 4);
    int* partials = (int*)alloc((size_t)NB * 4);
    unsigned short* Vb = (unsigned short*)alloc((size_t)LAYERS * HIDD * 512 * 2);
    unsigned short* Wcb = (unsigned short*)alloc((size_t)HIDD * UDIM * 2);
    float* ws = (float*)alloc((size_t)LAYERS * HEADS * HIDD * 4);
    float* wd = (float*)alloc((size_t)LAYERS * HEADS * HIDD * 4);
    float* bnsums = (float*)alloc((size_t)LAYERS * NSLICE * 256 * 4);
    (void)ws_size;

    hipMemsetAsync(deg, 0, (size_t)n * 4, stream);
    hipMemsetAsync(bnsums, 0, (size_t)LAYERS * NSLICE * 256 * 4, stream);
    if (n < MPAD) {
        hipMemsetAsync(u + (size_t)n * UDIM, 0, (size_t)(MPAD - n) * UDIM * 2, stream);
    }

    // weight precompute
    k_prep_v<<<(LAYERS * HIDD * 512 + 255) / 256, 256, 0, stream>>>(Wl, Vb);
    k_prep_a<<<(LAYERS * HEADS * HIDD + 255) / 256, 256, 0, stream>>>(Wl, a_src, a_dst, ws, wd);
    k_prep_wc<<<(HIDD * UDIM + 255) / 256, 256, 0, stream>>>(Wc, Wcb);

    // CSR build
    k_deg<<<(tot + 255) / 256, 256, 0, stream>>>(ei, deg, E, tot);
    k_scan1<<<NB, 256, 0, stream>>>(deg, rowptr, partials, n);
    k_scan2<<<1, 256, 0, stream>>>(partials, NB);
    k_scan3<<<NB, 256, 0, stream>>>(deg, partials, rowptr, cursor, n);
    k_scatter<<<(tot + 255) / 256, 256, 0, stream>>>(ei, cursor, csr_src, E, tot);

    // encoder
    k_enc<<<(n * EMBD + 255) / 256, 256, 0, stream>>>(x, emb, Wf, bf, u, n);
    k_gemm_enc<<<MPAD / 128, 256, 0, stream>>>(u, Wcb, bc, h, hb, n);
    k_al0<<<(n + 3) / 4, 256, 0, stream>>>(h, ws, wd, al_s, al_d, n);

    float invn = 1.0f / (float)n;
    int NLB = (n + 3) / 4;
    for (int l = 0; l < LAYERS; l++) {
        k_layer<<<NLB, 256, 0, stream>>>(rowptr, csr_src, al_s, al_d, hb,
                                         Vb + (size_t)l * HIDD * 512, agg,
                                         bnsums + (size_t)l * NSLICE * 256, n);
        if (l < LAYERS - 1)
            k_apply<0><<<(n + 3) / 4, 256, 0, stream>>>(
                agg, bnsums + (size_t)l * NSLICE * 256, gamma + l * HIDD, beta + l * HIDD,
                h, hb, ws + (size_t)(l + 1) * 512, wd + (size_t)(l + 1) * 512, al_s, al_d,
                nullptr, nullptr, nullptr, invn, n);
        else
            k_apply<1><<<(n + 3) / 4, 256, 0, stream>>>(
                agg, bnsums + (size_t)l * NSLICE * 256, gamma + l * HIDD, beta + l * HIDD,
                h, hb, nullptr, nullptr, nullptr, nullptr, Wout, bout, out, invn, n);
    }
}

// Round 11
// 802.992 us; speedup vs baseline: 1.2649x; 1.2649x over previous
//
#include <hip/hip_runtime.h>
#include <hip/hip_bf16.h>
#include <math.h>

#define INDIM 16
#define EMBD 32
#define UDIM 64
#define HIDD 128
#define HEADS 4
#define LAYERS 3
#define MPAD 50048  // 391 * 128
#define NSLICE 32   // bn-sum stripes (atomic contention reduction)

typedef short v8s __attribute__((ext_vector_type(8)));
typedef float v4f __attribute__((ext_vector_type(4)));

__device__ __forceinline__ float lrelu(float x) { return x > 0.f ? x : 0.2f * x; }
__device__ __forceinline__ float bf2f(unsigned int bits16) {
    unsigned int u = bits16 << 16;
    return __builtin_bit_cast(float, u);
}
__device__ __forceinline__ unsigned short f2bf(float f) {
    unsigned int u = __builtin_bit_cast(unsigned int, f);
    unsigned int lsb = (u >> 16) & 1;
    u += 0x7fff + lsb;  // round to nearest even
    return (unsigned short)(u >> 16);
}

// ---------------- encoder features: u = [emb, x@Wf^T + bf] in bf16 ----------------
__global__ __launch_bounds__(256) void k_enc(const float* __restrict__ x,
                                             const float* __restrict__ emb,
                                             const float* __restrict__ Wf,
                                             const float* __restrict__ bf,
                                             unsigned short* __restrict__ u, int n) {
    int i = blockIdx.x * 256 + threadIdx.x;
    if (i >= n * EMBD) return;
    int node = i >> 5, j = i & 31;
    const float* xr = x + (size_t)node * INDIM;
    const float* wr = Wf + (size_t)j * INDIM;
    float s = bf[j];
#pragma unroll
    for (int k = 0; k < INDIM; k++) s += xr[k] * wr[k];
    u[(size_t)node * UDIM + EMBD + j] = f2bf(s);
    u[(size_t)node * UDIM + j] = f2bf(emb[(size_t)node * EMBD + j]);
}

// ---------------- weight precompute ----------------
__global__ __launch_bounds__(256) void k_prep_v(const float* __restrict__ Wl,
                                                unsigned short* __restrict__ Vb) {
    int i = blockIdx.x * 256 + threadIdx.x;
    if (i >= LAYERS * HIDD * 512) return;
    int l = i >> 16;
    int rem = i & 65535;
    int c = rem >> 9;
    int f = rem & 511;
    int h = f >> 7, k = f & 127;
    Vb[i] = f2bf(Wl[(size_t)l * 512 * HIDD + (size_t)(h * HIDD + c) * HIDD + k]);
}

// ws[l][h][k] = sum_c a_s[l,h,c] * Wl[l][h*128+c][k]   (and wd for a_dst)
__global__ __launch_bounds__(256) void k_prep_a(const float* __restrict__ Wl,
                                                const float* __restrict__ a_s,
                                                const float* __restrict__ a_d,
                                                float* __restrict__ ws, float* __restrict__ wd) {
    int i = blockIdx.x * 256 + threadIdx.x;
    if (i >= LAYERS * HEADS * HIDD) return;
    int l = i >> 9, h = (i >> 7) & 3, k = i & 127;
    const float* W = Wl + (size_t)l * 512 * HIDD;
    const float* as = a_s + l * 512 + h * HIDD;
    const float* ad = a_d + l * 512 + h * HIDD;
    float ss = 0.f, sd = 0.f;
    for (int c = 0; c < HIDD; c++) {
        float w = W[(size_t)(h * HIDD + c) * HIDD + k];
        ss += as[c] * w;
        sd += ad[c] * w;
    }
    ws[i] = ss;
    wd[i] = sd;
}

__global__ __launch_bounds__(256) void k_prep_wc(const float* __restrict__ Wc,
                                                 unsigned short* __restrict__ Wcb) {
    int i = blockIdx.x * 256 + threadIdx.x;
    if (i < HIDD * UDIM) Wcb[i] = f2bf(Wc[i]);
}

// ---------------- encoder MFMA GEMM: O(M,128) = A(M,64) @ B(128,64)^T + bias, relu ----------------
__global__ __launch_bounds__(256) void k_gemm_enc(const unsigned short* __restrict__ A,
                                                  const unsigned short* __restrict__ B,
                                                  const float* __restrict__ bias,
                                                  float* __restrict__ O,
                                                  unsigned short* __restrict__ Ob, int M) {
    const int K = UDIM;
    int tid = threadIdx.x;
    int lane = tid & 63, wid = tid >> 6;
    int wm = wid >> 1, wn = wid & 1;
    int bm = blockIdx.x * 128;
    int lr = lane & 15, lk = lane >> 4;
    v4f acc[4][4] = {};
    const unsigned short* Abase = A + (size_t)(bm + wm * 64 + lr) * K + lk * 8;
    const unsigned short* Bbase = B + (size_t)(wn * 64 + lr) * K + lk * 8;
#pragma unroll
    for (int kk = 0; kk < K / 32; kk++) {
        v8s a[4], b[4];
#pragma unroll
        for (int f = 0; f < 4; f++) {
            a[f] = *(const v8s*)(Abase + (size_t)(f * 16) * K + kk * 32);
            b[f] = *(const v8s*)(Bbase + (size_t)(f * 16) * K + kk * 32);
        }
#pragma unroll
        for (int i = 0; i < 4; i++)
#pragma unroll
            for (int j = 0; j < 4; j++)
                acc[i][j] = __builtin_amdgcn_mfma_f32_16x16x32_bf16(a[i], b[j], acc[i][j], 0, 0, 0);
    }
#pragma unroll
    for (int i = 0; i < 4; i++) {
#pragma unroll
        for (int r = 0; r < 4; r++) {
            int row = bm + wm * 64 + i * 16 + lk * 4 + r;
            if (row >= M) continue;
#pragma unroll
            for (int j = 0; j < 4; j++) {
                int col = wn * 64 + j * 16 + lr;
                float v = fmaxf(acc[i][j][r] + bias[col], 0.f);
                O[(size_t)row * HIDD + col] = v;
                Ob[(size_t)row * HIDD + col] = f2bf(v);
            }
        }
    }
}

// ---------------- CSR build ----------------
__global__ __launch_bounds__(256) void k_deg(const int* __restrict__ ei, int* __restrict__ deg,
                                             int E, int tot) {
    int e = blockIdx.x * 256 + threadIdx.x;
    if (e >= tot) return;
    int dst = (e < E) ? ei[E + e] : (e - E);
    atomicAdd(&deg[dst], 1);
}

__global__ __launch_bounds__(256) void k_scan1(const int* __restrict__ deg,
                                               int* __restrict__ rowptr,
                                               int* __restrict__ partials, int n) {
    int tid = threadIdx.x;
    int i = blockIdx.x * 256 + tid;
    int v = (i < n) ? deg[i] : 0;
    __shared__ int sm[256];
    sm[tid] = v;
    __syncthreads();
    for (int off = 1; off < 256; off <<= 1) {
        int t = (tid >= off) ? sm[tid - off] : 0;
        __syncthreads();
        sm[tid] += t;
        __syncthreads();
    }
    if (i < n) rowptr[i] = sm[tid] - v;  // exclusive within block
    if (tid == 255) partials[blockIdx.x] = sm[255];
}

__global__ __launch_bounds__(256) void k_scan2(int* __restrict__ partials, int nb) {
    int tid = threadIdx.x;
    int v = (tid < nb) ? partials[tid] : 0;
    __shared__ int sm[256];
    sm[tid] = v;
    __syncthreads();
    for (int off = 1; off < 256; off <<= 1) {
        int t = (tid >= off) ? sm[tid - off] : 0;
        __syncthreads();
        sm[tid] += t;
        __syncthreads();
    }
    if (tid < nb) partials[tid] = sm[tid] - v;  // exclusive
}

__global__ __launch_bounds__(256) void k_scan3(const int* __restrict__ deg,
                                               const int* __restrict__ partials,
                                               int* __restrict__ rowptr,
                                               int* __restrict__ cursor, int n) {
    int i = blockIdx.x * 256 + threadIdx.x;
    if (i >= n) return;
    int r = rowptr[i] + partials[blockIdx.x];
    rowptr[i] = r;
    cursor[i] = r;
    if (i == n - 1) rowptr[n] = r + deg[i];
}

__global__ __launch_bounds__(256) void k_scatter(const int* __restrict__ ei, int* __restrict__ cursor,
                                                 int* __restrict__ csr_src, int E, int tot) {
    int e = blockIdx.x * 256 + threadIdx.x;
    if (e >= tot) return;
    int src = (e < E) ? ei[e] : (e - E);
    int dst = (e < E) ? ei[E + e] : (e - E);
    int pos = atomicAdd(&cursor[dst], 1);
    csr_src[pos] = src;
}

// ---------------- layer-0 attention logits from fp32 h ----------------
__global__ __launch_bounds__(256) void k_al0(const float* __restrict__ h,
                                             const float* __restrict__ ws,
                                             const float* __restrict__ wd,
                                             float* __restrict__ al_s, float* __restrict__ al_d,
                                             int n) {
    int wid = threadIdx.x >> 6, lane = threadIdx.x & 63;
    int node = blockIdx.x * 4 + wid;
    if (node >= n) return;
    float2 v = *(const float2*)(h + (size_t)node * HIDD + 2 * lane);
    float s[8];
#pragma unroll
    for (int hh = 0; hh < 4; hh++) {
        float2 w1 = *(const float2*)(ws + hh * HIDD + 2 * lane);
        float2 w2 = *(const float2*)(wd + hh * HIDD + 2 * lane);
        s[hh] = v.x * w1.x + v.y * w1.y;
        s[4 + hh] = v.x * w2.x + v.y * w2.y;
    }
#pragma unroll
    for (int o = 32; o; o >>= 1)
#pragma unroll
        for (int q = 0; q < 8; q++) s[q] += __shfl_xor(s[q], o);
    if (lane == 0) {
        *(float4*)(al_s + (size_t)node * 4) = make_float4(s[0], s[1], s[2], s[3]);
        *(float4*)(al_d + (size_t)node * 4) = make_float4(s[4], s[5], s[6], s[7]);
    }
}

// ---------------- fused layer (R9 structure) + ablation variants ----------------
// ABL 0: full (real path).  ABL 1: softmax only.  ABL 3: softmax + gather loads (no FMA).
// ABL 2: full Phase A (gather+FMA+G-write), no Phase B.  Variants write keep-alives to `agg`
// (scratch) so nothing is DCE'd; they never touch real outputs.
template <int ABL>
__global__ __launch_bounds__(1024) void k_layer(const int* __restrict__ rowptr,
                                                const int* __restrict__ csr_src,
                                                const float* __restrict__ al_s,
                                                const float* __restrict__ al_d,
                                                const unsigned short* __restrict__ hb,
                                                const unsigned short* __restrict__ Vb,
                                                float* __restrict__ agg,
                                                float* __restrict__ bns, int n) {
    __shared__ unsigned int Gw[16 * 256];
    __shared__ float s1[128], s2[128];
    __shared__ int Ssrc[16][64];
    __shared__ float Sal[16][4][64];
    int tid = threadIdx.x, lane = tid & 63, w = tid >> 6;
    if (tid < 128) { s1[tid] = 0.f; s2[tid] = 0.f; }
    int node0 = blockIdx.x * 16;
    int node = node0 + w;
    const float4* als4 = (const float4*)al_s;
    const unsigned int* h2 = (const unsigned int*)hb;
    int sw = (w & 7) << 2;

    if (node < n) {
        int start = rowptr[node], end = rowptr[node + 1];
        int deg = end - start;
        float4 ad = ((const float4*)al_d)[node];
        if (deg <= 64) {
            // ---- softmax: lane = edge ----
            bool act = lane < deg;
            int src_l = act ? csr_src[start + lane] : 0;
            float e0 = -3.0e38f, e1 = -3.0e38f, e2 = -3.0e38f, e3 = -3.0e38f;
            if (act) {
                float4 as = als4[src_l];
                e0 = lrelu(as.x + ad.x);
                e1 = lrelu(as.y + ad.y);
                e2 = lrelu(as.z + ad.z);
                e3 = lrelu(as.w + ad.w);
            }
            int span = 1;
            while (span < deg) span <<= 1;
            float m0 = e0, m1 = e1, m2 = e2, m3 = e3;
            for (int o = 1; o < span; o <<= 1) {
                m0 = fmaxf(m0, __shfl_xor(m0, o));
                m1 = fmaxf(m1, __shfl_xor(m1, o));
                m2 = fmaxf(m2, __shfl_xor(m2, o));
                m3 = fmaxf(m3, __shfl_xor(m3, o));
            }
            float p0 = act ? expf(e0 - m0) : 0.f;
            float p1 = act ? expf(e1 - m1) : 0.f;
            float p2 = act ? expf(e2 - m2) : 0.f;
            float p3 = act ? expf(e3 - m3) : 0.f;
            float t0 = p0, t1 = p1, t2 = p2, t3 = p3;
            for (int o = 1; o < span; o <<= 1) {
                t0 += __shfl_xor(t0, o);
                t1 += __shfl_xor(t1, o);
                t2 += __shfl_xor(t2, o);
                t3 += __shfl_xor(t3, o);
            }
            // stage src + alpha to wave-private LDS (inactive lanes: src=0, alpha=0)
            Ssrc[w][lane] = src_l;
            Sal[w][0][lane] = p0 / (t0 + 1e-16f);
            Sal[w][1][lane] = p1 / (t1 + 1e-16f);
            Sal[w][2][lane] = p2 / (t2 + 1e-16f);
            Sal[w][3][lane] = p3 / (t3 + 1e-16f);

            if (ABL == 1) {
                // softmax-only: keep staged values alive, skip gather/G/PhaseB
                agg[(size_t)node * 64 + lane] =
                    Sal[w][0][lane] + Sal[w][1][lane] + Sal[w][2][lane] + Sal[w][3][lane] +
                    (float)Ssrc[w][lane];
            } else if (ABL == 3) {
                // softmax + loads, no FMA: fold loads into xor to keep them alive
                unsigned int accx = 0;
                for (int j0 = 0; j0 < deg; j0 += 4) {
                    int4 s4 = *(const int4*)&Ssrc[w][j0];
                    float4 af0 = *(const float4*)&Sal[w][0][j0];
                    float4 af1 = *(const float4*)&Sal[w][1][j0];
                    float4 af2 = *(const float4*)&Sal[w][2][j0];
                    float4 af3 = *(const float4*)&Sal[w][3][j0];
                    unsigned int u0 = h2[(size_t)s4.x * 64 + lane];
                    unsigned int u1 = h2[(size_t)s4.y * 64 + lane];
                    unsigned int u2 = h2[(size_t)s4.z * 64 + lane];
                    unsigned int u3 = h2[(size_t)s4.w * 64 + lane];
                    accx ^= u0 ^ u1 ^ u2 ^ u3 ^
                            __builtin_bit_cast(unsigned int, af0.x + af1.y + af2.z + af3.w);
                }
                ((unsigned int*)agg)[(size_t)node * 64 + lane] = accx;
            } else {
                // ---- full pipelined gather: 4 edges per iteration, uniform LDS reads ----
                float acc[4][2] = {};
                for (int j0 = 0; j0 < deg; j0 += 4) {
                    int4 s4 = *(const int4*)&Ssrc[w][j0];
                    float4 af0 = *(const float4*)&Sal[w][0][j0];
                    float4 af1 = *(const float4*)&Sal[w][1][j0];
                    float4 af2 = *(const float4*)&Sal[w][2][j0];
                    float4 af3 = *(const float4*)&Sal[w][3][j0];
                    unsigned int u0 = h2[(size_t)s4.x * 64 + lane];
                    unsigned int u1 = h2[(size_t)s4.y * 64 + lane];
                    unsigned int u2 = h2[(size_t)s4.z * 64 + lane];
                    unsigned int u3 = h2[(size_t)s4.w * 64 + lane];
                    float x0, x1;
                    x0 = bf2f(u0 & 0xffff); x1 = bf2f(u0 >> 16);
                    acc[0][0] += af0.x * x0; acc[0][1] += af0.x * x1;
                    acc[1][0] += af1.x * x0; acc[1][1] += af1.x * x1;
                    acc[2][0] += af2.x * x0; acc[2][1] += af2.x * x1;
                    acc[3][0] += af3.x * x0; acc[3][1] += af3.x * x1;
                    x0 = bf2f(u1 & 0xffff); x1 = bf2f(u1 >> 16);
                    acc[0][0] += af0.y * x0; acc[0][1] += af0.y * x1;
                    acc[1][0] += af1.y * x0; acc[1][1] += af1.y * x1;
                    acc[2][0] += af2.y * x0; acc[2][1] += af2.y * x1;
                    acc[3][0] += af3.y * x0; acc[3][1] += af3.y * x1;
                    x0 = bf2f(u2 & 0xffff); x1 = bf2f(u2 >> 16);
                    acc[0][0] += af0.z * x0; acc[0][1] += af0.z * x1;
                    acc[1][0] += af1.z * x0; acc[1][1] += af1.z * x1;
                    acc[2][0] += af2.z * x0; acc[2][1] += af2.z * x1;
                    acc[3][0] += af3.z * x0; acc[3][1] += af3.z * x1;
                    x0 = bf2f(u3 & 0xffff); x1 = bf2f(u3 >> 16);
                    acc[0][0] += af0.w * x0; acc[0][1] += af0.w * x1;
                    acc[1][0] += af1.w * x0; acc[1][1] += af1.w * x1;
                    acc[2][0] += af2.w * x0; acc[2][1] += af2.w * x1;
                    acc[3][0] += af3.w * x0; acc[3][1] += af3.w * x1;
                }
#pragma unroll
                for (int hh = 0; hh < 4; hh++) {
                    unsigned int p = (unsigned int)f2bf(acc[hh][0]) |
                                     ((unsigned int)f2bf(acc[hh][1]) << 16);
                    Gw[w * 256 + ((hh * 64 + lane) ^ sw)] = p;
                }
            }
        } else {
            // ---- rare fallback: serial-broadcast gather (kept in all variants) ----
            float m0 = -3.0e38f, m1 = -3.0e38f, m2 = -3.0e38f, m3 = -3.0e38f;
            for (int j = start + lane; j < end; j += 64) {
                float4 as = als4[csr_src[j]];
                m0 = fmaxf(m0, lrelu(as.x + ad.x));
                m1 = fmaxf(m1, lrelu(as.y + ad.y));
                m2 = fmaxf(m2, lrelu(as.z + ad.z));
                m3 = fmaxf(m3, lrelu(as.w + ad.w));
            }
#pragma unroll
            for (int o = 32; o; o >>= 1) {
                m0 = fmaxf(m0, __shfl_xor(m0, o));
                m1 = fmaxf(m1, __shfl_xor(m1, o));
                m2 = fmaxf(m2, __shfl_xor(m2, o));
                m3 = fmaxf(m3, __shfl_xor(m3, o));
            }
            float t0 = 0.f, t1 = 0.f, t2 = 0.f, t3 = 0.f;
            for (int j = start + lane; j < end; j += 64) {
                float4 as = als4[csr_src[j]];
                t0 += expf(lrelu(as.x + ad.x) - m0);
                t1 += expf(lrelu(as.y + ad.y) - m1);
                t2 += expf(lrelu(as.z + ad.z) - m2);
                t3 += expf(lrelu(as.w + ad.w) - m3);
            }
#pragma unroll
            for (int o = 32; o; o >>= 1) {
                t0 += __shfl_xor(t0, o);
                t1 += __shfl_xor(t1, o);
                t2 += __shfl_xor(t2, o);
                t3 += __shfl_xor(t3, o);
            }
            float i0 = 1.f / (t0 + 1e-16f), i1 = 1.f / (t1 + 1e-16f);
            float i2 = 1.f / (t2 + 1e-16f), i3 = 1.f / (t3 + 1e-16f);
            float acc[4][2] = {};
            for (int base = start; base < end; base += 64) {
                int cnt = min(64, end - base);
                bool act2 = lane < cnt;
                int src_l = act2 ? csr_src[base + lane] : 0;
                float a0 = 0.f, a1 = 0.f, a2 = 0.f, a3 = 0.f;
                if (act2) {
                    float4 as = als4[src_l];
                    a0 = expf(lrelu(as.x + ad.x) - m0) * i0;
                    a1 = expf(lrelu(as.y + ad.y) - m1) * i1;
                    a2 = expf(lrelu(as.z + ad.z) - m2) * i2;
                    a3 = expf(lrelu(as.w + ad.w) - m3) * i3;
                }
                for (int jj = 0; jj < cnt; jj++) {
                    int sj = __shfl(src_l, jj);
                    float b0 = __shfl(a0, jj), b1 = __shfl(a1, jj);
                    float b2 = __shfl(a2, jj), b3 = __shfl(a3, jj);
                    unsigned int uu = h2[(size_t)sj * 64 + lane];
                    float x0 = bf2f(uu & 0xffff), x1 = bf2f(uu >> 16);
                    acc[0][0] += b0 * x0; acc[0][1] += b0 * x1;
                    acc[1][0] += b1 * x0; acc[1][1] += b1 * x1;
                    acc[2][0] += b2 * x0; acc[2][1] += b2 * x1;
                    acc[3][0] += b3 * x0; acc[3][1] += b3 * x1;
                }
            }
#pragma unroll
            for (int hh = 0; hh < 4; hh++) {
                unsigned int p = (unsigned int)f2bf(acc[hh][0]) |
                                 ((unsigned int)f2bf(acc[hh][1]) << 16);
                Gw[w * 256 + ((hh * 64 + lane) ^ sw)] = p;
            }
        }
    } else {
        // pad rows: zero
#pragma unroll
        for (int hh = 0; hh < 4; hh++) Gw[w * 256 + ((hh * 64 + lane) ^ sw)] = 0;
    }
    __syncthreads();

    if (ABL == 1 || ABL == 3) return;

    if (ABL == 2) {
        // keep G alive via LDS readback, skip MFMA/Vb/bns
        unsigned int v = Gw[tid] ^ Gw[tid + 1024] ^ Gw[tid + 2048] ^ Gw[tid + 3072];
        ((unsigned int*)agg)[(size_t)blockIdx.x * 1024 + tid] = v;
        return;
    }

    // ---- Phase B: agg(16x128) = G(16x512) @ Vb(128x512)^T; wave w<8 -> cols [w*16, w*16+16)
    if (w < 8) {
        int lr = lane & 15, lk = lane >> 4;
        int swr = (lr & 7) << 2;
        v4f a2 = {};
        const unsigned short* Bb = Vb + (size_t)(w * 16 + lr) * 512 + lk * 8;
#pragma unroll
        for (int kk = 0; kk < 16; kk++) {
            v8s a = *(const v8s*)(&Gw[lr * 256 + ((kk * 16 + lk * 4) ^ swr)]);
            v8s b = *(const v8s*)(Bb + kk * 32);
            a2 = __builtin_amdgcn_mfma_f32_16x16x32_bf16(a, b, a2, 0, 0, 0);
        }
        int col = w * 16 + lr;
        float ls = 0.f, lq = 0.f;
#pragma unroll
        for (int r = 0; r < 4; r++) {
            int nd = node0 + lk * 4 + r;
            float v = a2[r];
            if (nd < n) {
                agg[(size_t)nd * HIDD + col] = v;
                ls += v;
                lq += v * v;
            }
        }
        atomicAdd(&s1[col], ls);
        atomicAdd(&s2[col], lq);
    }
    __syncthreads();
    if (tid < 128) {
        float* slice = bns + (size_t)(blockIdx.x & (NSLICE - 1)) * 256;
        atomicAdd(&slice[tid], s1[tid]);
        atomicAdd(&slice[128 + tid], s2[tid]);
    }
}

// ---------------- fused BN finalize+apply + residual + (next-layer al | output head) --------
template <int MODE>
__global__ __launch_bounds__(256) void k_apply(const float* __restrict__ agg,
                                               const float* __restrict__ bns,
                                               const float* __restrict__ gamma,
                                               const float* __restrict__ beta,
                                               float* __restrict__ h,
                                               unsigned short* __restrict__ hb,
                                               const float* __restrict__ ws,
                                               const float* __restrict__ wd,
                                               float* __restrict__ al_s,
                                               float* __restrict__ al_d,
                                               const float* __restrict__ Wout,
                                               const float* __restrict__ bout,
                                               float* __restrict__ out,
                                               float invn, int n) {
    int wid = threadIdx.x >> 6, lane = threadIdx.x & 63;
    int node = blockIdx.x * 4 + wid;
    if (node >= n) return;
    int c0 = 2 * lane, c1 = 2 * lane + 1;
    float s0 = 0.f, q0 = 0.f, s1v = 0.f, q1v = 0.f;
    for (int sl = 0; sl < NSLICE; sl++) {
        float2 a = *(const float2*)(bns + sl * 256 + c0);
        float2 b = *(const float2*)(bns + sl * 256 + 128 + c0);
        s0 += a.x; s1v += a.y;
        q0 += b.x; q1v += b.y;
    }
    float mu0 = s0 * invn, mu1 = s1v * invn;
    float va0 = q0 * invn - mu0 * mu0;
    float va1 = q1v * invn - mu1 * mu1;
    float sc0 = gamma[c0] * rsqrtf(0.0625f * va0 + 1e-5f) * 0.25f;
    float sc1 = gamma[c1] * rsqrtf(0.0625f * va1 + 1e-5f) * 0.25f;
    float sh0 = beta[c0] - mu0 * sc0;
    float sh1 = beta[c1] - mu1 * sc1;

    float2 ag = *(const float2*)(agg + (size_t)node * HIDD + c0);
    float2 ho = *(const float2*)(h + (size_t)node * HIDD + c0);
    float v0 = fmaxf(ag.x * sc0 + sh0, 0.f) + ho.x;
    float v1 = fmaxf(ag.y * sc1 + sh1, 0.f) + ho.y;
    if (MODE == 0) {
        *(float2*)(h + (size_t)node * HIDD + c0) = make_float2(v0, v1);
        ((unsigned int*)hb)[(size_t)node * 64 + lane] =
            (unsigned int)f2bf(v0) | ((unsigned int)f2bf(v1) << 16);
        float s[8];
#pragma unroll
        for (int hh = 0; hh < 4; hh++) {
            float2 w1 = *(const float2*)(ws + hh * HIDD + c0);
            float2 w2 = *(const float2*)(wd + hh * HIDD + c0);
            s[hh] = v0 * w1.x + v1 * w1.y;
            s[4 + hh] = v0 * w2.x + v1 * w2.y;
        }
#pragma unroll
        for (int o = 32; o; o >>= 1)
#pragma unroll
            for (int q = 0; q < 8; q++) s[q] += __shfl_xor(s[q], o);
        if (lane == 0) {
            *(float4*)(al_s + (size_t)node * 4) = make_float4(s[0], s[1], s[2], s[3]);
            *(float4*)(al_d + (size_t)node * 4) = make_float4(s[4], s[5], s[6], s[7]);
        }
    } else {
        float2 w = *(const float2*)(Wout + c0);
        float p = v0 * w.x + v1 * w.y;
#pragma unroll
        for (int o = 32; o; o >>= 1) p += __shfl_xor(p, o);
        if (lane == 0) {
            float v = p + bout[0];
            out[node] = fminf(fmaxf(v, -10.f), 10.f);
        }
    }
}

extern "C" void kernel_launch(void* const* d_in, const int* in_sizes, int n_in,
                              void* d_out, int out_size, void* d_ws, size_t ws_size,
                              hipStream_t stream) {
    const float* x = (const float*)d_in[0];
    const int* ei = (const int*)d_in[1];
    const float* emb = (const float*)d_in[2];
    const float* Wf = (const float*)d_in[3];
    const float* bf = (const float*)d_in[4];
    const float* Wc = (const float*)d_in[5];
    const float* bc = (const float*)d_in[6];
    const float* Wl = (const float*)d_in[7];
    const float* a_src = (const float*)d_in[8];
    const float* a_dst = (const float*)d_in[9];
    // d_in[10] = bl : cancels in BN mean subtraction
    const float* gamma = (const float*)d_in[11];
    const float* beta = (const float*)d_in[12];
    const float* Wout = (const float*)d_in[13];
    const float* bout = (const float*)d_in[14];
    float* out = (float*)d_out;

    int n = in_sizes[0] / INDIM;  // 50000
    int E = in_sizes[1] / 2;      // 400000
    int tot = E + n;
    int NB = (n + 255) / 256;  // scan blocks

    size_t off = 0;
    auto alloc = [&](size_t bytes) {
        void* p = (char*)d_ws + off;
        off = (off + bytes + 255) & ~(size_t)255;
        return p;
    };
    unsigned short* u = (unsigned short*)alloc((size_t)MPAD * UDIM * 2);
    float* h = (float*)alloc((size_t)MPAD * HIDD * 4);
    unsigned short* hb = (unsigned short*)alloc((size_t)MPAD * HIDD * 2);
    float* agg = (float*)alloc((size_t)MPAD * HIDD * 4);
    float* al_s = (float*)alloc((size_t)n * HEADS * 4);
    float* al_d = (float*)alloc((size_t)n * HEADS * 4);
    int* deg = (int*)alloc((size_t)n * 4);
    int* rowptr = (int*)alloc(((size_t)n + 1) * 4);
    int* cursor = (int*)alloc((size_t)n * 4);
    int* csr_src = (int*)alloc((size_t)tot * 4);
    int* partials = (int*)alloc((size_t)NB * 4);
    unsigned short* Vb = (unsigned short*)alloc((size_t)LAYERS * HIDD * 512 * 2);
    unsigned short* Wcb = (unsigned short*)alloc((size_t)HIDD * UDIM * 2);
    float* ws = (float*)alloc((size_t)LAYERS * HEADS * HIDD * 4);
    float* wd = (float*)alloc((size_t)LAYERS * HEADS * HIDD * 4);
    float* bnsums = (float*)alloc((size_t)LAYERS * NSLICE * 256 * 4);
    float* ablsc = (float*)alloc((size_t)3200 * 1024 * 4);  // 13 MB ablation scratch
    (void)ws_size;

    hipMemsetAsync(deg, 0, (size_t)n * 4, stream);
    hipMemsetAsync(bnsums, 0, (size_t)LAYERS * NSLICE * 256 * 4, stream);
    if (n < MPAD) {
        hipMemsetAsync(u + (size_t)n * UDIM, 0, (size_t)(MPAD - n) * UDIM * 2, stream);
    }

    // weight precompute
    k_prep_v<<<(LAYERS * HIDD * 512 + 255) / 256, 256, 0, stream>>>(Wl, Vb);
    k_prep_a<<<(LAYERS * HEADS * HIDD + 255) / 256, 256, 0, stream>>>(Wl, a_src, a_dst, ws, wd);
    k_prep_wc<<<(HIDD * UDIM + 255) / 256, 256, 0, stream>>>(Wc, Wcb);

    // CSR build
    k_deg<<<(tot + 255) / 256, 256, 0, stream>>>(ei, deg, E, tot);
    k_scan1<<<NB, 256, 0, stream>>>(deg, rowptr, partials, n);
    k_scan2<<<1, 256, 0, stream>>>(partials, NB);
    k_scan3<<<NB, 256, 0, stream>>>(deg, partials, rowptr, cursor, n);
    k_scatter<<<(tot + 255) / 256, 256, 0, stream>>>(ei, cursor, csr_src, E, tot);

    // encoder
    k_enc<<<(n * EMBD + 255) / 256, 256, 0, stream>>>(x, emb, Wf, bf, u, n);
    k_gemm_enc<<<MPAD / 128, 256, 0, stream>>>(u, Wcb, bc, h, hb, n);
    k_al0<<<(n + 3) / 4, 256, 0, stream>>>(h, ws, wd, al_s, al_d, n);

    float invn = 1.0f / (float)n;
    int NLB = (n + 15) / 16;
    for (int l = 0; l < LAYERS; l++) {
        k_layer<0><<<NLB, 1024, 0, stream>>>(rowptr, csr_src, al_s, al_d, hb,
                                             Vb + (size_t)l * HIDD * 512, agg,
                                             bnsums + (size_t)l * NSLICE * 256, n);
        if (l < LAYERS - 1)
            k_apply<0><<<(n + 3) / 4, 256, 0, stream>>>(
                agg, bnsums + (size_t)l * NSLICE * 256, gamma + l * HIDD, beta + l * HIDD,
                h, hb, ws + (size_t)(l + 1) * 512, wd + (size_t)(l + 1) * 512, al_s, al_d,
                nullptr, nullptr, nullptr, invn, n);
        else
            k_apply<1><<<(n + 3) / 4, 256, 0, stream>>>(
                agg, bnsums + (size_t)l * NSLICE * 256, gamma + l * HIDD, beta + l * HIDD,
                h, hb, nullptr, nullptr, nullptr, nullptr, Wout, bout, out, invn, n);
    }

    // ---- instrumented ablations (outputs -> scratch; real outputs already written) ----
    // order: ABL1 (softmax only), ABL3 (softmax+loads), ABL2 (full Phase A, no Phase B)
    k_layer<1><<<NLB, 1024, 0, stream>>>(rowptr, csr_src, al_s, al_d, hb, Vb, ablsc, ablsc, n);
    k_layer<3><<<NLB, 1024, 0, stream>>>(rowptr, csr_src, al_s, al_d, hb, Vb, ablsc, ablsc, n);
    k_layer<2><<<NLB, 1024, 0, stream>>>(rowptr, csr_src, al_s, al_d, hb, Vb, ablsc, ablsc, n);
}

// Round 12
// 567.076 us; speedup vs baseline: 1.7911x; 1.4160x over previous
//
#include <hip/hip_runtime.h>
#include <hip/hip_bf16.h>
#include <math.h>

#define INDIM 16
#define EMBD 32
#define UDIM 64
#define HIDD 128
#define HEADS 4
#define LAYERS 3
#define MPAD 50048  // 391 * 128
#define NSLICE 32   // bn-sum stripes (atomic contention reduction)

typedef short v8s __attribute__((ext_vector_type(8)));
typedef float v4f __attribute__((ext_vector_type(4)));

__device__ __forceinline__ float lrelu(float x) { return x > 0.f ? x : 0.2f * x; }
__device__ __forceinline__ float bf2f(unsigned int bits16) {
    unsigned int u = bits16 << 16;
    return __builtin_bit_cast(float, u);
}
__device__ __forceinline__ unsigned short f2bf(float f) {
    unsigned int u = __builtin_bit_cast(unsigned int, f);
    unsigned int lsb = (u >> 16) & 1;
    u += 0x7fff + lsb;  // round to nearest even
    return (unsigned short)(u >> 16);
}

// ---------------- encoder features: u = [emb, x@Wf^T + bf] in bf16 ----------------
__global__ __launch_bounds__(256) void k_enc(const float* __restrict__ x,
                                             const float* __restrict__ emb,
                                             const float* __restrict__ Wf,
                                             const float* __restrict__ bf,
                                             unsigned short* __restrict__ u, int n) {
    int i = blockIdx.x * 256 + threadIdx.x;
    if (i >= n * EMBD) return;
    int node = i >> 5, j = i & 31;
    const float* xr = x + (size_t)node * INDIM;
    const float* wr = Wf + (size_t)j * INDIM;
    float s = bf[j];
#pragma unroll
    for (int k = 0; k < INDIM; k++) s += xr[k] * wr[k];
    u[(size_t)node * UDIM + EMBD + j] = f2bf(s);
    u[(size_t)node * UDIM + j] = f2bf(emb[(size_t)node * EMBD + j]);
}

// ---------------- weight precompute ----------------
__global__ __launch_bounds__(256) void k_prep_v(const float* __restrict__ Wl,
                                                unsigned short* __restrict__ Vb) {
    int i = blockIdx.x * 256 + threadIdx.x;
    if (i >= LAYERS * HIDD * 512) return;
    int l = i >> 16;
    int rem = i & 65535;
    int c = rem >> 9;
    int f = rem & 511;
    int h = f >> 7, k = f & 127;
    Vb[i] = f2bf(Wl[(size_t)l * 512 * HIDD + (size_t)(h * HIDD + c) * HIDD + k]);
}

// ws[l][h][k] = sum_c a_s[l,h,c] * Wl[l][h*128+c][k]   (and wd for a_dst)
__global__ __launch_bounds__(256) void k_prep_a(const float* __restrict__ Wl,
                                                const float* __restrict__ a_s,
                                                const float* __restrict__ a_d,
                                                float* __restrict__ ws, float* __restrict__ wd) {
    int i = blockIdx.x * 256 + threadIdx.x;
    if (i >= LAYERS * HEADS * HIDD) return;
    int l = i >> 9, h = (i >> 7) & 3, k = i & 127;
    const float* W = Wl + (size_t)l * 512 * HIDD;
    const float* as = a_s + l * 512 + h * HIDD;
    const float* ad = a_d + l * 512 + h * HIDD;
    float ss = 0.f, sd = 0.f;
    for (int c = 0; c < HIDD; c++) {
        float w = W[(size_t)(h * HIDD + c) * HIDD + k];
        ss += as[c] * w;
        sd += ad[c] * w;
    }
    ws[i] = ss;
    wd[i] = sd;
}

__global__ __launch_bounds__(256) void k_prep_wc(const float* __restrict__ Wc,
                                                 unsigned short* __restrict__ Wcb) {
    int i = blockIdx.x * 256 + threadIdx.x;
    if (i < HIDD * UDIM) Wcb[i] = f2bf(Wc[i]);
}

// ---------------- encoder MFMA GEMM: O(M,128) = A(M,64) @ B(128,64)^T + bias, relu ----------------
__global__ __launch_bounds__(256) void k_gemm_enc(const unsigned short* __restrict__ A,
                                                  const unsigned short* __restrict__ B,
                                                  const float* __restrict__ bias,
                                                  float* __restrict__ O,
                                                  unsigned short* __restrict__ Ob, int M) {
    const int K = UDIM;
    int tid = threadIdx.x;
    int lane = tid & 63, wid = tid >> 6;
    int wm = wid >> 1, wn = wid & 1;
    int bm = blockIdx.x * 128;
    int lr = lane & 15, lk = lane >> 4;
    v4f acc[4][4] = {};
    const unsigned short* Abase = A + (size_t)(bm + wm * 64 + lr) * K + lk * 8;
    const unsigned short* Bbase = B + (size_t)(wn * 64 + lr) * K + lk * 8;
#pragma unroll
    for (int kk = 0; kk < K / 32; kk++) {
        v8s a[4], b[4];
#pragma unroll
        for (int f = 0; f < 4; f++) {
            a[f] = *(const v8s*)(Abase + (size_t)(f * 16) * K + kk * 32);
            b[f] = *(const v8s*)(Bbase + (size_t)(f * 16) * K + kk * 32);
        }
#pragma unroll
        for (int i = 0; i < 4; i++)
#pragma unroll
            for (int j = 0; j < 4; j++)
                acc[i][j] = __builtin_amdgcn_mfma_f32_16x16x32_bf16(a[i], b[j], acc[i][j], 0, 0, 0);
    }
#pragma unroll
    for (int i = 0; i < 4; i++) {
#pragma unroll
        for (int r = 0; r < 4; r++) {
            int row = bm + wm * 64 + i * 16 + lk * 4 + r;
            if (row >= M) continue;
#pragma unroll
            for (int j = 0; j < 4; j++) {
                int col = wn * 64 + j * 16 + lr;
                float v = fmaxf(acc[i][j][r] + bias[col], 0.f);
                O[(size_t)row * HIDD + col] = v;
                Ob[(size_t)row * HIDD + col] = f2bf(v);
            }
        }
    }
}

// ---------------- CSR build ----------------
__global__ __launch_bounds__(256) void k_deg(const int* __restrict__ ei, int* __restrict__ deg,
                                             int E, int tot) {
    int e = blockIdx.x * 256 + threadIdx.x;
    if (e >= tot) return;
    int dst = (e < E) ? ei[E + e] : (e - E);
    atomicAdd(&deg[dst], 1);
}

__global__ __launch_bounds__(256) void k_scan1(const int* __restrict__ deg,
                                               int* __restrict__ rowptr,
                                               int* __restrict__ partials, int n) {
    int tid = threadIdx.x;
    int i = blockIdx.x * 256 + tid;
    int v = (i < n) ? deg[i] : 0;
    __shared__ int sm[256];
    sm[tid] = v;
    __syncthreads();
    for (int off = 1; off < 256; off <<= 1) {
        int t = (tid >= off) ? sm[tid - off] : 0;
        __syncthreads();
        sm[tid] += t;
        __syncthreads();
    }
    if (i < n) rowptr[i] = sm[tid] - v;  // exclusive within block
    if (tid == 255) partials[blockIdx.x] = sm[255];
}

__global__ __launch_bounds__(256) void k_scan2(int* __restrict__ partials, int nb) {
    int tid = threadIdx.x;
    int v = (tid < nb) ? partials[tid] : 0;
    __shared__ int sm[256];
    sm[tid] = v;
    __syncthreads();
    for (int off = 1; off < 256; off <<= 1) {
        int t = (tid >= off) ? sm[tid - off] : 0;
        __syncthreads();
        sm[tid] += t;
        __syncthreads();
    }
    if (tid < nb) partials[tid] = sm[tid] - v;  // exclusive
}

__global__ __launch_bounds__(256) void k_scan3(const int* __restrict__ deg,
                                               const int* __restrict__ partials,
                                               int* __restrict__ rowptr,
                                               int* __restrict__ cursor, int n) {
    int i = blockIdx.x * 256 + threadIdx.x;
    if (i >= n) return;
    int r = rowptr[i] + partials[blockIdx.x];
    rowptr[i] = r;
    cursor[i] = r;
    if (i == n - 1) rowptr[n] = r + deg[i];
}

__global__ __launch_bounds__(256) void k_scatter(const int* __restrict__ ei, int* __restrict__ cursor,
                                                 int* __restrict__ csr_src, int E, int tot) {
    int e = blockIdx.x * 256 + threadIdx.x;
    if (e >= tot) return;
    int src = (e < E) ? ei[e] : (e - E);
    int dst = (e < E) ? ei[E + e] : (e - E);
    int pos = atomicAdd(&cursor[dst], 1);
    csr_src[pos] = src;
}

// ---------------- layer-0 attention logits from fp32 h ----------------
__global__ __launch_bounds__(256) void k_al0(const float* __restrict__ h,
                                             const float* __restrict__ ws,
                                             const float* __restrict__ wd,
                                             float* __restrict__ al_s, float* __restrict__ al_d,
                                             int n) {
    int wid = threadIdx.x >> 6, lane = threadIdx.x & 63;
    int node = blockIdx.x * 4 + wid;
    if (node >= n) return;
    float2 v = *(const float2*)(h + (size_t)node * HIDD + 2 * lane);
    float s[8];
#pragma unroll
    for (int hh = 0; hh < 4; hh++) {
        float2 w1 = *(const float2*)(ws + hh * HIDD + 2 * lane);
        float2 w2 = *(const float2*)(wd + hh * HIDD + 2 * lane);
        s[hh] = v.x * w1.x + v.y * w1.y;
        s[4 + hh] = v.x * w2.x + v.y * w2.y;
    }
#pragma unroll
    for (int o = 32; o; o >>= 1)
#pragma unroll
        for (int q = 0; q < 8; q++) s[q] += __shfl_xor(s[q], o);
    if (lane == 0) {
        *(float4*)(al_s + (size_t)node * 4) = make_float4(s[0], s[1], s[2], s[3]);
        *(float4*)(al_d + (size_t)node * 4) = make_float4(s[4], s[5], s[6], s[7]);
    }
}

// ---------------- fused layer (R9 structure) + ablation variants ----------------
// ABL 0: full (real path).  ABL 1: softmax only.  ABL 3: softmax + gather loads (no FMA).
// ABL 2: full Phase A (gather+FMA+G-write), no Phase B.
template <int ABL>
__global__ __launch_bounds__(1024) void k_layer(const int* __restrict__ rowptr,
                                                const int* __restrict__ csr_src,
                                                const float* __restrict__ al_s,
                                                const float* __restrict__ al_d,
                                                const unsigned short* __restrict__ hb,
                                                const unsigned short* __restrict__ Vb,
                                                float* __restrict__ agg,
                                                float* __restrict__ bns, int n) {
    __shared__ unsigned int Gw[16 * 256];
    __shared__ float s1[128], s2[128];
    __shared__ int Ssrc[16][64];
    __shared__ float Sal[16][4][64];
    int tid = threadIdx.x, lane = tid & 63, w = tid >> 6;
    if (tid < 128) { s1[tid] = 0.f; s2[tid] = 0.f; }
    int node0 = blockIdx.x * 16;
    int node = node0 + w;
    const float4* als4 = (const float4*)al_s;
    const unsigned int* h2 = (const unsigned int*)hb;
    int sw = (w & 7) << 2;

    if (node < n) {
        int start = rowptr[node], end = rowptr[node + 1];
        int deg = end - start;
        float4 ad = ((const float4*)al_d)[node];
        if (deg <= 64) {
            // ---- softmax: lane = edge ----
            bool act = lane < deg;
            int src_l = act ? csr_src[start + lane] : 0;
            float e0 = -3.0e38f, e1 = -3.0e38f, e2 = -3.0e38f, e3 = -3.0e38f;
            if (act) {
                float4 as = als4[src_l];
                e0 = lrelu(as.x + ad.x);
                e1 = lrelu(as.y + ad.y);
                e2 = lrelu(as.z + ad.z);
                e3 = lrelu(as.w + ad.w);
            }
            int span = 1;
            while (span < deg) span <<= 1;
            float m0 = e0, m1 = e1, m2 = e2, m3 = e3;
            for (int o = 1; o < span; o <<= 1) {
                m0 = fmaxf(m0, __shfl_xor(m0, o));
                m1 = fmaxf(m1, __shfl_xor(m1, o));
                m2 = fmaxf(m2, __shfl_xor(m2, o));
                m3 = fmaxf(m3, __shfl_xor(m3, o));
            }
            float p0 = act ? expf(e0 - m0) : 0.f;
            float p1 = act ? expf(e1 - m1) : 0.f;
            float p2 = act ? expf(e2 - m2) : 0.f;
            float p3 = act ? expf(e3 - m3) : 0.f;
            float t0 = p0, t1 = p1, t2 = p2, t3 = p3;
            for (int o = 1; o < span; o <<= 1) {
                t0 += __shfl_xor(t0, o);
                t1 += __shfl_xor(t1, o);
                t2 += __shfl_xor(t2, o);
                t3 += __shfl_xor(t3, o);
            }
            // stage src + alpha to wave-private LDS (inactive lanes: src=0, alpha=0)
            Ssrc[w][lane] = src_l;
            Sal[w][0][lane] = p0 / (t0 + 1e-16f);
            Sal[w][1][lane] = p1 / (t1 + 1e-16f);
            Sal[w][2][lane] = p2 / (t2 + 1e-16f);
            Sal[w][3][lane] = p3 / (t3 + 1e-16f);

            if (ABL == 1) {
                agg[(size_t)node * 64 + lane] =
                    Sal[w][0][lane] + Sal[w][1][lane] + Sal[w][2][lane] + Sal[w][3][lane] +
                    (float)Ssrc[w][lane];
            } else if (ABL == 3) {
                unsigned int accx = 0;
                for (int j0 = 0; j0 < deg; j0 += 4) {
                    int4 s4 = *(const int4*)&Ssrc[w][j0];
                    float4 af0 = *(const float4*)&Sal[w][0][j0];
                    float4 af1 = *(const float4*)&Sal[w][1][j0];
                    float4 af2 = *(const float4*)&Sal[w][2][j0];
                    float4 af3 = *(const float4*)&Sal[w][3][j0];
                    unsigned int u0 = h2[(size_t)s4.x * 64 + lane];
                    unsigned int u1 = h2[(size_t)s4.y * 64 + lane];
                    unsigned int u2 = h2[(size_t)s4.z * 64 + lane];
                    unsigned int u3 = h2[(size_t)s4.w * 64 + lane];
                    accx ^= u0 ^ u1 ^ u2 ^ u3 ^
                            __builtin_bit_cast(unsigned int, af0.x + af1.y + af2.z + af3.w);
                }
                ((unsigned int*)agg)[(size_t)node * 64 + lane] = accx;
            } else {
                // ---- full pipelined gather: 4 edges per iteration, uniform LDS reads ----
                float acc[4][2] = {};
                for (int j0 = 0; j0 < deg; j0 += 4) {
                    int4 s4 = *(const int4*)&Ssrc[w][j0];
                    float4 af0 = *(const float4*)&Sal[w][0][j0];
                    float4 af1 = *(const float4*)&Sal[w][1][j0];
                    float4 af2 = *(const float4*)&Sal[w][2][j0];
                    float4 af3 = *(const float4*)&Sal[w][3][j0];
                    unsigned int u0 = h2[(size_t)s4.x * 64 + lane];
                    unsigned int u1 = h2[(size_t)s4.y * 64 + lane];
                    unsigned int u2 = h2[(size_t)s4.z * 64 + lane];
                    unsigned int u3 = h2[(size_t)s4.w * 64 + lane];
                    float x0, x1;
                    x0 = bf2f(u0 & 0xffff); x1 = bf2f(u0 >> 16);
                    acc[0][0] += af0.x * x0; acc[0][1] += af0.x * x1;
                    acc[1][0] += af1.x * x0; acc[1][1] += af1.x * x1;
                    acc[2][0] += af2.x * x0; acc[2][1] += af2.x * x1;
                    acc[3][0] += af3.x * x0; acc[3][1] += af3.x * x1;
                    x0 = bf2f(u1 & 0xffff); x1 = bf2f(u1 >> 16);
                    acc[0][0] += af0.y * x0; acc[0][1] += af0.y * x1;
                    acc[1][0] += af1.y * x0; acc[1][1] += af1.y * x1;
                    acc[2][0] += af2.y * x0; acc[2][1] += af2.y * x1;
                    acc[3][0] += af3.y * x0; acc[3][1] += af3.y * x1;
                    x0 = bf2f(u2 & 0xffff); x1 = bf2f(u2 >> 16);
                    acc[0][0] += af0.z * x0; acc[0][1] += af0.z * x1;
                    acc[1][0] += af1.z * x0; acc[1][1] += af1.z * x1;
                    acc[2][0] += af2.z * x0; acc[2][1] += af2.z * x1;
                    acc[3][0] += af3.z * x0; acc[3][1] += af3.z * x1;
                    x0 = bf2f(u3 & 0xffff); x1 = bf2f(u3 >> 16);
                    acc[0][0] += af0.w * x0; acc[0][1] += af0.w * x1;
                    acc[1][0] += af1.w * x0; acc[1][1] += af1.w * x1;
                    acc[2][0] += af2.w * x0; acc[2][1] += af2.w * x1;
                    acc[3][0] += af3.w * x0; acc[3][1] += af3.w * x1;
                }
#pragma unroll
                for (int hh = 0; hh < 4; hh++) {
                    unsigned int p = (unsigned int)f2bf(acc[hh][0]) |
                                     ((unsigned int)f2bf(acc[hh][1]) << 16);
                    Gw[w * 256 + ((hh * 64 + lane) ^ sw)] = p;
                }
            }
        } else {
            // ---- rare fallback: serial-broadcast gather (kept in all variants) ----
            float m0 = -3.0e38f, m1 = -3.0e38f, m2 = -3.0e38f, m3 = -3.0e38f;
            for (int j = start + lane; j < end; j += 64) {
                float4 as = als4[csr_src[j]];
                m0 = fmaxf(m0, lrelu(as.x + ad.x));
                m1 = fmaxf(m1, lrelu(as.y + ad.y));
                m2 = fmaxf(m2, lrelu(as.z + ad.z));
                m3 = fmaxf(m3, lrelu(as.w + ad.w));
            }
#pragma unroll
            for (int o = 32; o; o >>= 1) {
                m0 = fmaxf(m0, __shfl_xor(m0, o));
                m1 = fmaxf(m1, __shfl_xor(m1, o));
                m2 = fmaxf(m2, __shfl_xor(m2, o));
                m3 = fmaxf(m3, __shfl_xor(m3, o));
            }
            float t0 = 0.f, t1 = 0.f, t2 = 0.f, t3 = 0.f;
            for (int j = start + lane; j < end; j += 64) {
                float4 as = als4[csr_src[j]];
                t0 += expf(lrelu(as.x + ad.x) - m0);
                t1 += expf(lrelu(as.y + ad.y) - m1);
                t2 += expf(lrelu(as.z + ad.z) - m2);
                t3 += expf(lrelu(as.w + ad.w) - m3);
            }
#pragma unroll
            for (int o = 32; o; o >>= 1) {
                t0 += __shfl_xor(t0, o);
                t1 += __shfl_xor(t1, o);
                t2 += __shfl_xor(t2, o);
                t3 += __shfl_xor(t3, o);
            }
            float i0 = 1.f / (t0 + 1e-16f), i1 = 1.f / (t1 + 1e-16f);
            float i2 = 1.f / (t2 + 1e-16f), i3 = 1.f / (t3 + 1e-16f);
            float acc[4][2] = {};
            for (int base = start; base < end; base += 64) {
                int cnt = min(64, end - base);
                bool act2 = lane < cnt;
                int src_l = act2 ? csr_src[base + lane] : 0;
                float a0 = 0.f, a1 = 0.f, a2 = 0.f, a3 = 0.f;
                if (act2) {
                    float4 as = als4[src_l];
                    a0 = expf(lrelu(as.x + ad.x) - m0) * i0;
                    a1 = expf(lrelu(as.y + ad.y) - m1) * i1;
                    a2 = expf(lrelu(as.z + ad.z) - m2) * i2;
                    a3 = expf(lrelu(as.w + ad.w) - m3) * i3;
                }
                for (int jj = 0; jj < cnt; jj++) {
                    int sj = __shfl(src_l, jj);
                    float b0 = __shfl(a0, jj), b1 = __shfl(a1, jj);
                    float b2 = __shfl(a2, jj), b3 = __shfl(a3, jj);
                    unsigned int uu = h2[(size_t)sj * 64 + lane];
                    float x0 = bf2f(uu & 0xffff), x1 = bf2f(uu >> 16);
                    acc[0][0] += b0 * x0; acc[0][1] += b0 * x1;
                    acc[1][0] += b1 * x0; acc[1][1] += b1 * x1;
                    acc[2][0] += b2 * x0; acc[2][1] += b2 * x1;
                    acc[3][0] += b3 * x0; acc[3][1] += b3 * x1;
                }
            }
#pragma unroll
            for (int hh = 0; hh < 4; hh++) {
                unsigned int p = (unsigned int)f2bf(acc[hh][0]) |
                                 ((unsigned int)f2bf(acc[hh][1]) << 16);
                Gw[w * 256 + ((hh * 64 + lane) ^ sw)] = p;
            }
        }
    } else {
        // pad rows: zero
#pragma unroll
        for (int hh = 0; hh < 4; hh++) Gw[w * 256 + ((hh * 64 + lane) ^ sw)] = 0;
    }
    __syncthreads();

    if (ABL == 1 || ABL == 3) return;

    if (ABL == 2) {
        unsigned int v = Gw[tid] ^ Gw[tid + 1024] ^ Gw[tid + 2048] ^ Gw[tid + 3072];
        ((unsigned int*)agg)[(size_t)blockIdx.x * 1024 + tid] = v;
        return;
    }

    // ---- Phase B: agg(16x128) = G(16x512) @ Vb(128x512)^T; wave w<8 -> cols [w*16, w*16+16)
    if (w < 8) {
        int lr = lane & 15, lk = lane >> 4;
        int swr = (lr & 7) << 2;
        v4f a2 = {};
        const unsigned short* Bb = Vb + (size_t)(w * 16 + lr) * 512 + lk * 8;
#pragma unroll
        for (int kk = 0; kk < 16; kk++) {
            v8s a = *(const v8s*)(&Gw[lr * 256 + ((kk * 16 + lk * 4) ^ swr)]);
            v8s b = *(const v8s*)(Bb + kk * 32);
            a2 = __builtin_amdgcn_mfma_f32_16x16x32_bf16(a, b, a2, 0, 0, 0);
        }
        int col = w * 16 + lr;
        float ls = 0.f, lq = 0.f;
#pragma unroll
        for (int r = 0; r < 4; r++) {
            int nd = node0 + lk * 4 + r;
            float v = a2[r];
            if (nd < n) {
                agg[(size_t)nd * HIDD + col] = v;
                ls += v;
                lq += v * v;
            }
        }
        atomicAdd(&s1[col], ls);
        atomicAdd(&s2[col], lq);
    }
    __syncthreads();
    if (tid < 128) {
        float* slice = bns + (size_t)(blockIdx.x & (NSLICE - 1)) * 256;
        atomicAdd(&slice[tid], s1[tid]);
        atomicAdd(&slice[128 + tid], s2[tid]);
    }
}

// ---------------- BN finalize: reduce NSLICE stripes -> scale/shift (1 block) ----------------
__global__ __launch_bounds__(128) void k_bnfin(const float* __restrict__ bns,
                                               const float* __restrict__ gamma,
                                               const float* __restrict__ beta,
                                               float* __restrict__ scale,
                                               float* __restrict__ shift, float invn) {
    int c = threadIdx.x;
    float s = 0.f, q = 0.f;
    for (int sl = 0; sl < NSLICE; sl++) {
        s += bns[sl * 256 + c];
        q += bns[sl * 256 + 128 + c];
    }
    float mu = s * invn;
    float var = q * invn - mu * mu;
    float sc = gamma[c] * rsqrtf(0.0625f * var + 1e-5f) * 0.25f;  // 0.25 head-mean folded
    scale[c] = sc;
    shift[c] = beta[c] - mu * sc;
}

// ---------------- fused BN apply + residual + (next-layer al | output head) ----------------
template <int MODE>
__global__ __launch_bounds__(256) void k_apply(const float* __restrict__ agg,
                                               const float* __restrict__ scale,
                                               const float* __restrict__ shift,
                                               float* __restrict__ h,
                                               unsigned short* __restrict__ hb,
                                               const float* __restrict__ ws,
                                               const float* __restrict__ wd,
                                               float* __restrict__ al_s,
                                               float* __restrict__ al_d,
                                               const float* __restrict__ Wout,
                                               const float* __restrict__ bout,
                                               float* __restrict__ out, int n) {
    int wid = threadIdx.x >> 6, lane = threadIdx.x & 63;
    int node = blockIdx.x * 4 + wid;
    if (node >= n) return;
    int c0 = 2 * lane, c1 = 2 * lane + 1;
    float2 ag = *(const float2*)(agg + (size_t)node * HIDD + c0);
    float2 ho = *(const float2*)(h + (size_t)node * HIDD + c0);
    float v0 = fmaxf(ag.x * scale[c0] + shift[c0], 0.f) + ho.x;
    float v1 = fmaxf(ag.y * scale[c1] + shift[c1], 0.f) + ho.y;
    if (MODE == 0) {
        *(float2*)(h + (size_t)node * HIDD + c0) = make_float2(v0, v1);
        ((unsigned int*)hb)[(size_t)node * 64 + lane] =
            (unsigned int)f2bf(v0) | ((unsigned int)f2bf(v1) << 16);
        float s[8];
#pragma unroll
        for (int hh = 0; hh < 4; hh++) {
            float2 w1 = *(const float2*)(ws + hh * HIDD + c0);
            float2 w2 = *(const float2*)(wd + hh * HIDD + c0);
            s[hh] = v0 * w1.x + v1 * w1.y;
            s[4 + hh] = v0 * w2.x + v1 * w2.y;
        }
#pragma unroll
        for (int o = 32; o; o >>= 1)
#pragma unroll
            for (int q = 0; q < 8; q++) s[q] += __shfl_xor(s[q], o);
        if (lane == 0) {
            *(float4*)(al_s + (size_t)node * 4) = make_float4(s[0], s[1], s[2], s[3]);
            *(float4*)(al_d + (size_t)node * 4) = make_float4(s[4], s[5], s[6], s[7]);
        }
    } else {
        float2 w = *(const float2*)(Wout + c0);
        float p = v0 * w.x + v1 * w.y;
#pragma unroll
        for (int o = 32; o; o >>= 1) p += __shfl_xor(p, o);
        if (lane == 0) {
            float v = p + bout[0];
            out[node] = fminf(fmaxf(v, -10.f), 10.f);
        }
    }
}

extern "C" void kernel_launch(void* const* d_in, const int* in_sizes, int n_in,
                              void* d_out, int out_size, void* d_ws, size_t ws_size,
                              hipStream_t stream) {
    const float* x = (const float*)d_in[0];
    const int* ei = (const int*)d_in[1];
    const float* emb = (const float*)d_in[2];
    const float* Wf = (const float*)d_in[3];
    const float* bf = (const float*)d_in[4];
    const float* Wc = (const float*)d_in[5];
    const float* bc = (const float*)d_in[6];
    const float* Wl = (const float*)d_in[7];
    const float* a_src = (const float*)d_in[8];
    const float* a_dst = (const float*)d_in[9];
    // d_in[10] = bl : cancels in BN mean subtraction
    const float* gamma = (const float*)d_in[11];
    const float* beta = (const float*)d_in[12];
    const float* Wout = (const float*)d_in[13];
    const float* bout = (const float*)d_in[14];
    float* out = (float*)d_out;

    int n = in_sizes[0] / INDIM;  // 50000
    int E = in_sizes[1] / 2;      // 400000
    int tot = E + n;
    int NB = (n + 255) / 256;  // scan blocks

    size_t off = 0;
    auto alloc = [&](size_t bytes) {
        void* p = (char*)d_ws + off;
        off = (off + bytes + 255) & ~(size_t)255;
        return p;
    };
    unsigned short* u = (unsigned short*)alloc((size_t)MPAD * UDIM * 2);
    float* h = (float*)alloc((size_t)MPAD * HIDD * 4);
    unsigned short* hb = (unsigned short*)alloc((size_t)MPAD * HIDD * 2);
    float* agg = (float*)alloc((size_t)MPAD * HIDD * 4);
    float* al_s = (float*)alloc((size_t)n * HEADS * 4);
    float* al_d = (float*)alloc((size_t)n * HEADS * 4);
    int* deg = (int*)alloc((size_t)n * 4);
    int* rowptr = (int*)alloc(((size_t)n + 1) * 4);
    int* cursor = (int*)alloc((size_t)n * 4);
    int* csr_src = (int*)alloc((size_t)tot * 4);
    int* partials = (int*)alloc((size_t)NB * 4);
    unsigned short* Vb = (unsigned short*)alloc((size_t)LAYERS * HIDD * 512 * 2);
    unsigned short* Wcb = (unsigned short*)alloc((size_t)HIDD * UDIM * 2);
    float* ws = (float*)alloc((size_t)LAYERS * HEADS * HIDD * 4);
    float* wd = (float*)alloc((size_t)LAYERS * HEADS * HIDD * 4);
    float* bnsums = (float*)alloc((size_t)LAYERS * NSLICE * 256 * 4);
    float* scale = (float*)alloc(128 * 4);
    float* shift = (float*)alloc(128 * 4);
    float* ablsc = (float*)alloc((size_t)3200 * 1024 * 4);  // 13 MB ablation scratch
    (void)ws_size;

    hipMemsetAsync(deg, 0, (size_t)n * 4, stream);
    hipMemsetAsync(bnsums, 0, (size_t)LAYERS * NSLICE * 256 * 4, stream);
    if (n < MPAD) {
        hipMemsetAsync(u + (size_t)n * UDIM, 0, (size_t)(MPAD - n) * UDIM * 2, stream);
    }

    // weight precompute
    k_prep_v<<<(LAYERS * HIDD * 512 + 255) / 256, 256, 0, stream>>>(Wl, Vb);
    k_prep_a<<<(LAYERS * HEADS * HIDD + 255) / 256, 256, 0, stream>>>(Wl, a_src, a_dst, ws, wd);
    k_prep_wc<<<(HIDD * UDIM + 255) / 256, 256, 0, stream>>>(Wc, Wcb);

    // CSR build
    k_deg<<<(tot + 255) / 256, 256, 0, stream>>>(ei, deg, E, tot);
    k_scan1<<<NB, 256, 0, stream>>>(deg, rowptr, partials, n);
    k_scan2<<<1, 256, 0, stream>>>(partials, NB);
    k_scan3<<<NB, 256, 0, stream>>>(deg, partials, rowptr, cursor, n);
    k_scatter<<<(tot + 255) / 256, 256, 0, stream>>>(ei, cursor, csr_src, E, tot);

    // encoder
    k_enc<<<(n * EMBD + 255) / 256, 256, 0, stream>>>(x, emb, Wf, bf, u, n);
    k_gemm_enc<<<MPAD / 128, 256, 0, stream>>>(u, Wcb, bc, h, hb, n);
    k_al0<<<(n + 3) / 4, 256, 0, stream>>>(h, ws, wd, al_s, al_d, n);

    float invn = 1.0f / (float)n;
    int NLB = (n + 15) / 16;
    for (int l = 0; l < LAYERS; l++) {
        k_layer<0><<<NLB, 1024, 0, stream>>>(rowptr, csr_src, al_s, al_d, hb,
                                             Vb + (size_t)l * HIDD * 512, agg,
                                             bnsums + (size_t)l * NSLICE * 256, n);
        k_bnfin<<<1, 128, 0, stream>>>(bnsums + (size_t)l * NSLICE * 256, gamma + l * HIDD,
                                       beta + l * HIDD, scale, shift, invn);
        if (l < LAYERS - 1)
            k_apply<0><<<(n + 3) / 4, 256, 0, stream>>>(
                agg, scale, shift, h, hb,
                ws + (size_t)(l + 1) * 512, wd + (size_t)(l + 1) * 512, al_s, al_d,
                nullptr, nullptr, nullptr, n);
        else
            k_apply<1><<<(n + 3) / 4, 256, 0, stream>>>(
                agg, scale, shift, h, hb,
                nullptr, nullptr, nullptr, nullptr, Wout, bout, out, n);
    }

    // ---- instrumented ablations (outputs -> scratch; real outputs already written) ----
    // order: ABL1 (softmax only), ABL3 (softmax+loads), ABL2 (full Phase A, no Phase B)
    k_layer<1><<<NLB, 1024, 0, stream>>>(rowptr, csr_src, al_s, al_d, hb, Vb, ablsc, ablsc, n);
    k_layer<3><<<NLB, 1024, 0, stream>>>(rowptr, csr_src, al_s, al_d, hb, Vb, ablsc, ablsc, n);
    k_layer<2><<<NLB, 1024, 0, stream>>>(rowptr, csr_src, al_s, al_d, hb, Vb, ablsc, ablsc, n);
}

// Round 13
// 522.723 us; speedup vs baseline: 1.9431x; 1.0849x over previous
//
#include <hip/hip_runtime.h>
#include <hip/hip_bf16.h>
#include <math.h>

#define INDIM 16
#define EMBD 32
#define UDIM 64
#define HIDD 128
#define HEADS 4
#define LAYERS 3
#define MPAD 50048  // 391 * 128
#define NSLICE 32   // bn-sum stripes (atomic contention reduction)

typedef short v8s __attribute__((ext_vector_type(8)));
typedef float v4f __attribute__((ext_vector_type(4)));

__device__ __forceinline__ float lrelu(float x) { return x > 0.f ? x : 0.2f * x; }
__device__ __forceinline__ float bf2f(unsigned int bits16) {
    unsigned int u = bits16 << 16;
    return __builtin_bit_cast(float, u);
}
__device__ __forceinline__ unsigned short f2bf(float f) {
    unsigned int u = __builtin_bit_cast(unsigned int, f);
    unsigned int lsb = (u >> 16) & 1;
    u += 0x7fff + lsb;  // round to nearest even
    return (unsigned short)(u >> 16);
}

// ---------------- encoder features: u = [emb, x@Wf^T + bf] in bf16 ----------------
__global__ __launch_bounds__(256) void k_enc(const float* __restrict__ x,
                                             const float* __restrict__ emb,
                                             const float* __restrict__ Wf,
                                             const float* __restrict__ bf,
                                             unsigned short* __restrict__ u, int n) {
    int i = blockIdx.x * 256 + threadIdx.x;
    if (i >= n * EMBD) return;
    int node = i >> 5, j = i & 31;
    const float* xr = x + (size_t)node * INDIM;
    const float* wr = Wf + (size_t)j * INDIM;
    float s = bf[j];
#pragma unroll
    for (int k = 0; k < INDIM; k++) s += xr[k] * wr[k];
    u[(size_t)node * UDIM + EMBD + j] = f2bf(s);
    u[(size_t)node * UDIM + j] = f2bf(emb[(size_t)node * EMBD + j]);
}

// ---------------- weight precompute ----------------
__global__ __launch_bounds__(256) void k_prep_v(const float* __restrict__ Wl,
                                                unsigned short* __restrict__ Vb) {
    int i = blockIdx.x * 256 + threadIdx.x;
    if (i >= LAYERS * HIDD * 512) return;
    int l = i >> 16;
    int rem = i & 65535;
    int c = rem >> 9;
    int f = rem & 511;
    int h = f >> 7, k = f & 127;
    Vb[i] = f2bf(Wl[(size_t)l * 512 * HIDD + (size_t)(h * HIDD + c) * HIDD + k]);
}

// ws[l][h][k] = sum_c a_s[l,h,c] * Wl[l][h*128+c][k]   (and wd for a_dst)
__global__ __launch_bounds__(256) void k_prep_a(const float* __restrict__ Wl,
                                                const float* __restrict__ a_s,
                                                const float* __restrict__ a_d,
                                                float* __restrict__ ws, float* __restrict__ wd) {
    int i = blockIdx.x * 256 + threadIdx.x;
    if (i >= LAYERS * HEADS * HIDD) return;
    int l = i >> 9, h = (i >> 7) & 3, k = i & 127;
    const float* W = Wl + (size_t)l * 512 * HIDD;
    const float* as = a_s + l * 512 + h * HIDD;
    const float* ad = a_d + l * 512 + h * HIDD;
    float ss = 0.f, sd = 0.f;
    for (int c = 0; c < HIDD; c++) {
        float w = W[(size_t)(h * HIDD + c) * HIDD + k];
        ss += as[c] * w;
        sd += ad[c] * w;
    }
    ws[i] = ss;
    wd[i] = sd;
}

__global__ __launch_bounds__(256) void k_prep_wc(const float* __restrict__ Wc,
                                                 unsigned short* __restrict__ Wcb) {
    int i = blockIdx.x * 256 + threadIdx.x;
    if (i < HIDD * UDIM) Wcb[i] = f2bf(Wc[i]);
}

// ---------------- encoder MFMA GEMM: O(M,128) = A(M,64) @ B(128,64)^T + bias, relu ----------------
__global__ __launch_bounds__(256) void k_gemm_enc(const unsigned short* __restrict__ A,
                                                  const unsigned short* __restrict__ B,
                                                  const float* __restrict__ bias,
                                                  float* __restrict__ O,
                                                  unsigned short* __restrict__ Ob, int M) {
    const int K = UDIM;
    int tid = threadIdx.x;
    int lane = tid & 63, wid = tid >> 6;
    int wm = wid >> 1, wn = wid & 1;
    int bm = blockIdx.x * 128;
    int lr = lane & 15, lk = lane >> 4;
    v4f acc[4][4] = {};
    const unsigned short* Abase = A + (size_t)(bm + wm * 64 + lr) * K + lk * 8;
    const unsigned short* Bbase = B + (size_t)(wn * 64 + lr) * K + lk * 8;
#pragma unroll
    for (int kk = 0; kk < K / 32; kk++) {
        v8s a[4], b[4];
#pragma unroll
        for (int f = 0; f < 4; f++) {
            a[f] = *(const v8s*)(Abase + (size_t)(f * 16) * K + kk * 32);
            b[f] = *(const v8s*)(Bbase + (size_t)(f * 16) * K + kk * 32);
        }
#pragma unroll
        for (int i = 0; i < 4; i++)
#pragma unroll
            for (int j = 0; j < 4; j++)
                acc[i][j] = __builtin_amdgcn_mfma_f32_16x16x32_bf16(a[i], b[j], acc[i][j], 0, 0, 0);
    }
#pragma unroll
    for (int i = 0; i < 4; i++) {
#pragma unroll
        for (int r = 0; r < 4; r++) {
            int row = bm + wm * 64 + i * 16 + lk * 4 + r;
            if (row >= M) continue;
#pragma unroll
            for (int j = 0; j < 4; j++) {
                int col = wn * 64 + j * 16 + lr;
                float v = fmaxf(acc[i][j][r] + bias[col], 0.f);
                O[(size_t)row * HIDD + col] = v;
                Ob[(size_t)row * HIDD + col] = f2bf(v);
            }
        }
    }
}

// ---------------- CSR build ----------------
__global__ __launch_bounds__(256) void k_deg(const int* __restrict__ ei, int* __restrict__ deg,
                                             int E, int tot) {
    int e = blockIdx.x * 256 + threadIdx.x;
    if (e >= tot) return;
    int dst = (e < E) ? ei[E + e] : (e - E);
    atomicAdd(&deg[dst], 1);
}

__global__ __launch_bounds__(256) void k_scan1(const int* __restrict__ deg,
                                               int* __restrict__ rowptr,
                                               int* __restrict__ partials, int n) {
    int tid = threadIdx.x;
    int i = blockIdx.x * 256 + tid;
    int v = (i < n) ? deg[i] : 0;
    __shared__ int sm[256];
    sm[tid] = v;
    __syncthreads();
    for (int off = 1; off < 256; off <<= 1) {
        int t = (tid >= off) ? sm[tid - off] : 0;
        __syncthreads();
        sm[tid] += t;
        __syncthreads();
    }
    if (i < n) rowptr[i] = sm[tid] - v;  // exclusive within block
    if (tid == 255) partials[blockIdx.x] = sm[255];
}

__global__ __launch_bounds__(256) void k_scan2(int* __restrict__ partials, int nb) {
    int tid = threadIdx.x;
    int v = (tid < nb) ? partials[tid] : 0;
    __shared__ int sm[256];
    sm[tid] = v;
    __syncthreads();
    for (int off = 1; off < 256; off <<= 1) {
        int t = (tid >= off) ? sm[tid - off] : 0;
        __syncthreads();
        sm[tid] += t;
        __syncthreads();
    }
    if (tid < nb) partials[tid] = sm[tid] - v;  // exclusive
}

__global__ __launch_bounds__(256) void k_scan3(const int* __restrict__ deg,
                                               const int* __restrict__ partials,
                                               int* __restrict__ rowptr,
                                               int* __restrict__ cursor, int n) {
    int i = blockIdx.x * 256 + threadIdx.x;
    if (i >= n) return;
    int r = rowptr[i] + partials[blockIdx.x];
    rowptr[i] = r;
    cursor[i] = r;
    if (i == n - 1) rowptr[n] = r + deg[i];
}

__global__ __launch_bounds__(256) void k_scatter(const int* __restrict__ ei, int* __restrict__ cursor,
                                                 int* __restrict__ csr_src, int E, int tot) {
    int e = blockIdx.x * 256 + threadIdx.x;
    if (e >= tot) return;
    int src = (e < E) ? ei[e] : (e - E);
    int dst = (e < E) ? ei[E + e] : (e - E);
    int pos = atomicAdd(&cursor[dst], 1);
    csr_src[pos] = src;
}

// ---------------- layer-0 attention logits from fp32 h ----------------
__global__ __launch_bounds__(256) void k_al0(const float* __restrict__ h,
                                             const float* __restrict__ ws,
                                             const float* __restrict__ wd,
                                             float* __restrict__ al_s, float* __restrict__ al_d,
                                             int n) {
    int wid = threadIdx.x >> 6, lane = threadIdx.x & 63;
    int node = blockIdx.x * 4 + wid;
    if (node >= n) return;
    float2 v = *(const float2*)(h + (size_t)node * HIDD + 2 * lane);
    float s[8];
#pragma unroll
    for (int hh = 0; hh < 4; hh++) {
        float2 w1 = *(const float2*)(ws + hh * HIDD + 2 * lane);
        float2 w2 = *(const float2*)(wd + hh * HIDD + 2 * lane);
        s[hh] = v.x * w1.x + v.y * w1.y;
        s[4 + hh] = v.x * w2.x + v.y * w2.y;
    }
#pragma unroll
    for (int o = 32; o; o >>= 1)
#pragma unroll
        for (int q = 0; q < 8; q++) s[q] += __shfl_xor(s[q], o);
    if (lane == 0) {
        *(float4*)(al_s + (size_t)node * 4) = make_float4(s[0], s[1], s[2], s[3]);
        *(float4*)(al_d + (size_t)node * 4) = make_float4(s[4], s[5], s[6], s[7]);
    }
}

// ---------------- fused layer: softmax + 8-wide pipelined gather + MFMA + BN stats ----------
// Phase B diet: per-wave cols are disjoint -> (ls,lq) reduced via shfl_xor(16/32), lk==0 lane
// atomics straight into striped global bns. No s1/s2 LDS stage, no final barrier.
__global__ __launch_bounds__(1024) void k_layer(const int* __restrict__ rowptr,
                                                const int* __restrict__ csr_src,
                                                const float* __restrict__ al_s,
                                                const float* __restrict__ al_d,
                                                const unsigned short* __restrict__ hb,
                                                const unsigned short* __restrict__ Vb,
                                                float* __restrict__ agg,
                                                float* __restrict__ bns, int n) {
    __shared__ unsigned int Gw[16 * 256];
    __shared__ int Ssrc[16][64];
    __shared__ float Sal[16][4][64];
    int tid = threadIdx.x, lane = tid & 63, w = tid >> 6;
    int node0 = blockIdx.x * 16;
    int node = node0 + w;
    const float4* als4 = (const float4*)al_s;
    const unsigned int* h2 = (const unsigned int*)hb;
    int sw = (w & 7) << 2;

    if (node < n) {
        int start = rowptr[node], end = rowptr[node + 1];
        int deg = end - start;
        float4 ad = ((const float4*)al_d)[node];
        if (deg <= 64) {
            // ---- softmax: lane = edge ----
            bool act = lane < deg;
            int src_l = act ? csr_src[start + lane] : 0;
            float e0 = -3.0e38f, e1 = -3.0e38f, e2 = -3.0e38f, e3 = -3.0e38f;
            if (act) {
                float4 as = als4[src_l];
                e0 = lrelu(as.x + ad.x);
                e1 = lrelu(as.y + ad.y);
                e2 = lrelu(as.z + ad.z);
                e3 = lrelu(as.w + ad.w);
            }
            int span = 1;
            while (span < deg) span <<= 1;
            float m0 = e0, m1 = e1, m2 = e2, m3 = e3;
            for (int o = 1; o < span; o <<= 1) {
                m0 = fmaxf(m0, __shfl_xor(m0, o));
                m1 = fmaxf(m1, __shfl_xor(m1, o));
                m2 = fmaxf(m2, __shfl_xor(m2, o));
                m3 = fmaxf(m3, __shfl_xor(m3, o));
            }
            float p0 = act ? expf(e0 - m0) : 0.f;
            float p1 = act ? expf(e1 - m1) : 0.f;
            float p2 = act ? expf(e2 - m2) : 0.f;
            float p3 = act ? expf(e3 - m3) : 0.f;
            float t0 = p0, t1 = p1, t2 = p2, t3 = p3;
            for (int o = 1; o < span; o <<= 1) {
                t0 += __shfl_xor(t0, o);
                t1 += __shfl_xor(t1, o);
                t2 += __shfl_xor(t2, o);
                t3 += __shfl_xor(t3, o);
            }
            // stage src + alpha to wave-private LDS (inactive lanes: src=0, alpha=0)
            Ssrc[w][lane] = src_l;
            Sal[w][0][lane] = p0 / (t0 + 1e-16f);
            Sal[w][1][lane] = p1 / (t1 + 1e-16f);
            Sal[w][2][lane] = p2 / (t2 + 1e-16f);
            Sal[w][3][lane] = p3 / (t3 + 1e-16f);

            // ---- 8-wide pipelined gather: 8 row loads in flight, optimal bf16 unpack ----
            float2 acc2[4] = {};
            for (int j0 = 0; j0 < deg; j0 += 8) {
                int4 sA = *(const int4*)&Ssrc[w][j0];
                int4 sB = *(const int4*)&Ssrc[w][j0 + 4];
                unsigned int u0 = h2[(size_t)sA.x * 64 + lane];
                unsigned int u1 = h2[(size_t)sA.y * 64 + lane];
                unsigned int u2 = h2[(size_t)sA.z * 64 + lane];
                unsigned int u3 = h2[(size_t)sA.w * 64 + lane];
                unsigned int u4 = h2[(size_t)sB.x * 64 + lane];
                unsigned int u5 = h2[(size_t)sB.y * 64 + lane];
                unsigned int u6 = h2[(size_t)sB.z * 64 + lane];
                unsigned int u7 = h2[(size_t)sB.w * 64 + lane];
                float4 a0A = *(const float4*)&Sal[w][0][j0];
                float4 a1A = *(const float4*)&Sal[w][1][j0];
                float4 a2A = *(const float4*)&Sal[w][2][j0];
                float4 a3A = *(const float4*)&Sal[w][3][j0];
                float4 a0B = *(const float4*)&Sal[w][0][j0 + 4];
                float4 a1B = *(const float4*)&Sal[w][1][j0 + 4];
                float4 a2B = *(const float4*)&Sal[w][2][j0 + 4];
                float4 a3B = *(const float4*)&Sal[w][3][j0 + 4];
#define EDGE_FMA(u, b0, b1, b2, b3)                                              \
    {                                                                            \
        float xlo = __builtin_bit_cast(float, (u) << 16);                        \
        float xhi = __builtin_bit_cast(float, (u) & 0xffff0000u);                \
        acc2[0].x = fmaf(b0, xlo, acc2[0].x);                                    \
        acc2[0].y = fmaf(b0, xhi, acc2[0].y);                                    \
        acc2[1].x = fmaf(b1, xlo, acc2[1].x);                                    \
        acc2[1].y = fmaf(b1, xhi, acc2[1].y);                                    \
        acc2[2].x = fmaf(b2, xlo, acc2[2].x);                                    \
        acc2[2].y = fmaf(b2, xhi, acc2[2].y);                                    \
        acc2[3].x = fmaf(b3, xlo, acc2[3].x);                                    \
        acc2[3].y = fmaf(b3, xhi, acc2[3].y);                                    \
    }
                EDGE_FMA(u0, a0A.x, a1A.x, a2A.x, a3A.x)
                EDGE_FMA(u1, a0A.y, a1A.y, a2A.y, a3A.y)
                EDGE_FMA(u2, a0A.z, a1A.z, a2A.z, a3A.z)
                EDGE_FMA(u3, a0A.w, a1A.w, a2A.w, a3A.w)
                EDGE_FMA(u4, a0B.x, a1B.x, a2B.x, a3B.x)
                EDGE_FMA(u5, a0B.y, a1B.y, a2B.y, a3B.y)
                EDGE_FMA(u6, a0B.z, a1B.z, a2B.z, a3B.z)
                EDGE_FMA(u7, a0B.w, a1B.w, a2B.w, a3B.w)
#undef EDGE_FMA
            }
#pragma unroll
            for (int hh = 0; hh < 4; hh++) {
                unsigned int p = (unsigned int)f2bf(acc2[hh].x) |
                                 ((unsigned int)f2bf(acc2[hh].y) << 16);
                Gw[w * 256 + ((hh * 64 + lane) ^ sw)] = p;
            }
        } else {
            // ---- rare fallback: serial-broadcast gather ----
            float m0 = -3.0e38f, m1 = -3.0e38f, m2 = -3.0e38f, m3 = -3.0e38f;
            for (int j = start + lane; j < end; j += 64) {
                float4 as = als4[csr_src[j]];
                m0 = fmaxf(m0, lrelu(as.x + ad.x));
                m1 = fmaxf(m1, lrelu(as.y + ad.y));
                m2 = fmaxf(m2, lrelu(as.z + ad.z));
                m3 = fmaxf(m3, lrelu(as.w + ad.w));
            }
#pragma unroll
            for (int o = 32; o; o >>= 1) {
                m0 = fmaxf(m0, __shfl_xor(m0, o));
                m1 = fmaxf(m1, __shfl_xor(m1, o));
                m2 = fmaxf(m2, __shfl_xor(m2, o));
                m3 = fmaxf(m3, __shfl_xor(m3, o));
            }
            float t0 = 0.f, t1 = 0.f, t2 = 0.f, t3 = 0.f;
            for (int j = start + lane; j < end; j += 64) {
                float4 as = als4[csr_src[j]];
                t0 += expf(lrelu(as.x + ad.x) - m0);
                t1 += expf(lrelu(as.y + ad.y) - m1);
                t2 += expf(lrelu(as.z + ad.z) - m2);
                t3 += expf(lrelu(as.w + ad.w) - m3);
            }
#pragma unroll
            for (int o = 32; o; o >>= 1) {
                t0 += __shfl_xor(t0, o);
                t1 += __shfl_xor(t1, o);
                t2 += __shfl_xor(t2, o);
                t3 += __shfl_xor(t3, o);
            }
            float i0 = 1.f / (t0 + 1e-16f), i1 = 1.f / (t1 + 1e-16f);
            float i2 = 1.f / (t2 + 1e-16f), i3 = 1.f / (t3 + 1e-16f);
            float acc[4][2] = {};
            for (int base = start; base < end; base += 64) {
                int cnt = min(64, end - base);
                bool act2 = lane < cnt;
                int src_l = act2 ? csr_src[base + lane] : 0;
                float a0 = 0.f, a1 = 0.f, a2 = 0.f, a3 = 0.f;
                if (act2) {
                    float4 as = als4[src_l];
                    a0 = expf(lrelu(as.x + ad.x) - m0) * i0;
                    a1 = expf(lrelu(as.y + ad.y) - m1) * i1;
                    a2 = expf(lrelu(as.z + ad.z) - m2) * i2;
                    a3 = expf(lrelu(as.w + ad.w) - m3) * i3;
                }
                for (int jj = 0; jj < cnt; jj++) {
                    int sj = __shfl(src_l, jj);
                    float b0 = __shfl(a0, jj), b1 = __shfl(a1, jj);
                    float b2 = __shfl(a2, jj), b3 = __shfl(a3, jj);
                    unsigned int uu = h2[(size_t)sj * 64 + lane];
                    float x0 = bf2f(uu & 0xffff), x1 = bf2f(uu >> 16);
                    acc[0][0] += b0 * x0; acc[0][1] += b0 * x1;
                    acc[1][0] += b1 * x0; acc[1][1] += b1 * x1;
                    acc[2][0] += b2 * x0; acc[2][1] += b2 * x1;
                    acc[3][0] += b3 * x0; acc[3][1] += b3 * x1;
                }
            }
#pragma unroll
            for (int hh = 0; hh < 4; hh++) {
                unsigned int p = (unsigned int)f2bf(acc[hh][0]) |
                                 ((unsigned int)f2bf(acc[hh][1]) << 16);
                Gw[w * 256 + ((hh * 64 + lane) ^ sw)] = p;
            }
        }
    } else {
        // pad rows: zero
#pragma unroll
        for (int hh = 0; hh < 4; hh++) Gw[w * 256 + ((hh * 64 + lane) ^ sw)] = 0;
    }
    __syncthreads();

    // ---- Phase B: agg(16x128) = G(16x512) @ Vb(128x512)^T; wave w<8 -> cols [w*16, w*16+16)
    if (w < 8) {
        int lr = lane & 15, lk = lane >> 4;
        int swr = (lr & 7) << 2;
        v4f a2 = {};
        const unsigned short* Bb = Vb + (size_t)(w * 16 + lr) * 512 + lk * 8;
#pragma unroll
        for (int kk = 0; kk < 16; kk++) {
            v8s a = *(const v8s*)(&Gw[lr * 256 + ((kk * 16 + lk * 4) ^ swr)]);
            v8s b = *(const v8s*)(Bb + kk * 32);
            a2 = __builtin_amdgcn_mfma_f32_16x16x32_bf16(a, b, a2, 0, 0, 0);
        }
        int col = w * 16 + lr;
        float ls = 0.f, lq = 0.f;
#pragma unroll
        for (int r = 0; r < 4; r++) {
            int nd = node0 + lk * 4 + r;
            float v = a2[r];
            if (nd < n) {
                agg[(size_t)nd * HIDD + col] = v;
                ls += v;
                lq += v * v;
            }
        }
        // reduce over the 4 lanes (lk=0..3) sharing this col, then one global atomic
        ls += __shfl_xor(ls, 16); lq += __shfl_xor(lq, 16);
        ls += __shfl_xor(ls, 32); lq += __shfl_xor(lq, 32);
        if (lk == 0) {
            float* slice = bns + (size_t)(blockIdx.x & (NSLICE - 1)) * 256;
            atomicAdd(&slice[col], ls);
            atomicAdd(&slice[128 + col], lq);
        }
    }
}

// ---------------- BN finalize: reduce NSLICE stripes -> scale/shift (1 block) ----------------
__global__ __launch_bounds__(128) void k_bnfin(const float* __restrict__ bns,
                                               const float* __restrict__ gamma,
                                               const float* __restrict__ beta,
                                               float* __restrict__ scale,
                                               float* __restrict__ shift, float invn) {
    int c = threadIdx.x;
    float s = 0.f, q = 0.f;
    for (int sl = 0; sl < NSLICE; sl++) {
        s += bns[sl * 256 + c];
        q += bns[sl * 256 + 128 + c];
    }
    float mu = s * invn;
    float var = q * invn - mu * mu;
    float sc = gamma[c] * rsqrtf(0.0625f * var + 1e-5f) * 0.25f;  // 0.25 head-mean folded
    scale[c] = sc;
    shift[c] = beta[c] - mu * sc;
}

// ---------------- fused BN apply + residual + (next-layer al | output head) ----------------
template <int MODE>
__global__ __launch_bounds__(256) void k_apply(const float* __restrict__ agg,
                                               const float* __restrict__ scale,
                                               const float* __restrict__ shift,
                                               float* __restrict__ h,
                                               unsigned short* __restrict__ hb,
                                               const float* __restrict__ ws,
                                               const float* __restrict__ wd,
                                               float* __restrict__ al_s,
                                               float* __restrict__ al_d,
                                               const float* __restrict__ Wout,
                                               const float* __restrict__ bout,
                                               float* __restrict__ out, int n) {
    int wid = threadIdx.x >> 6, lane = threadIdx.x & 63;
    int node = blockIdx.x * 4 + wid;
    if (node >= n) return;
    int c0 = 2 * lane, c1 = 2 * lane + 1;
    float2 ag = *(const float2*)(agg + (size_t)node * HIDD + c0);
    float2 ho = *(const float2*)(h + (size_t)node * HIDD + c0);
    float v0 = fmaxf(ag.x * scale[c0] + shift[c0], 0.f) + ho.x;
    float v1 = fmaxf(ag.y * scale[c1] + shift[c1], 0.f) + ho.y;
    if (MODE == 0) {
        *(float2*)(h + (size_t)node * HIDD + c0) = make_float2(v0, v1);
        ((unsigned int*)hb)[(size_t)node * 64 + lane] =
            (unsigned int)f2bf(v0) | ((unsigned int)f2bf(v1) << 16);
        float s[8];
#pragma unroll
        for (int hh = 0; hh < 4; hh++) {
            float2 w1 = *(const float2*)(ws + hh * HIDD + c0);
            float2 w2 = *(const float2*)(wd + hh * HIDD + c0);
            s[hh] = v0 * w1.x + v1 * w1.y;
            s[4 + hh] = v0 * w2.x + v1 * w2.y;
        }
#pragma unroll
        for (int o = 32; o; o >>= 1)
#pragma unroll
            for (int q = 0; q < 8; q++) s[q] += __shfl_xor(s[q], o);
        if (lane == 0) {
            *(float4*)(al_s + (size_t)node * 4) = make_float4(s[0], s[1], s[2], s[3]);
            *(float4*)(al_d + (size_t)node * 4) = make_float4(s[4], s[5], s[6], s[7]);
        }
    } else {
        float2 w = *(const float2*)(Wout + c0);
        float p = v0 * w.x + v1 * w.y;
#pragma unroll
        for (int o = 32; o; o >>= 1) p += __shfl_xor(p, o);
        if (lane == 0) {
            float v = p + bout[0];
            out[node] = fminf(fmaxf(v, -10.f), 10.f);
        }
    }
}

extern "C" void kernel_launch(void* const* d_in, const int* in_sizes, int n_in,
                              void* d_out, int out_size, void* d_ws, size_t ws_size,
                              hipStream_t stream) {
    const float* x = (const float*)d_in[0];
    const int* ei = (const int*)d_in[1];
    const float* emb = (const float*)d_in[2];
    const float* Wf = (const float*)d_in[3];
    const float* bf = (const float*)d_in[4];
    const float* Wc = (const float*)d_in[5];
    const float* bc = (const float*)d_in[6];
    const float* Wl = (const float*)d_in[7];
    const float* a_src = (const float*)d_in[8];
    const float* a_dst = (const float*)d_in[9];
    // d_in[10] = bl : cancels in BN mean subtraction
    const float* gamma = (const float*)d_in[11];
    const float* beta = (const float*)d_in[12];
    const float* Wout = (const float*)d_in[13];
    const float* bout = (const float*)d_in[14];
    float* out = (float*)d_out;

    int n = in_sizes[0] / INDIM;  // 50000
    int E = in_sizes[1] / 2;      // 400000
    int tot = E + n;
    int NB = (n + 255) / 256;  // scan blocks

    size_t off = 0;
    auto alloc = [&](size_t bytes) {
        void* p = (char*)d_ws + off;
        off = (off + bytes + 255) & ~(size_t)255;
        return p;
    };
    unsigned short* u = (unsigned short*)alloc((size_t)MPAD * UDIM * 2);
    float* h = (float*)alloc((size_t)MPAD * HIDD * 4);
    unsigned short* hb = (unsigned short*)alloc((size_t)MPAD * HIDD * 2);
    float* agg = (float*)alloc((size_t)MPAD * HIDD * 4);
    float* al_s = (float*)alloc((size_t)n * HEADS * 4);
    float* al_d = (float*)alloc((size_t)n * HEADS * 4);
    int* deg = (int*)alloc((size_t)n * 4);
    int* rowptr = (int*)alloc(((size_t)n + 1) * 4);
    int* cursor = (int*)alloc((size_t)n * 4);
    int* csr_src = (int*)alloc((size_t)tot * 4);
    int* partials = (int*)alloc((size_t)NB * 4);
    unsigned short* Vb = (unsigned short*)alloc((size_t)LAYERS * HIDD * 512 * 2);
    unsigned short* Wcb = (unsigned short*)alloc((size_t)HIDD * UDIM * 2);
    float* ws = (float*)alloc((size_t)LAYERS * HEADS * HIDD * 4);
    float* wd = (float*)alloc((size_t)LAYERS * HEADS * HIDD * 4);
    float* bnsums = (float*)alloc((size_t)LAYERS * NSLICE * 256 * 4);
    float* scale = (float*)alloc(128 * 4);
    float* shift = (float*)alloc(128 * 4);
    (void)ws_size;

    hipMemsetAsync(deg, 0, (size_t)n * 4, stream);
    hipMemsetAsync(bnsums, 0, (size_t)LAYERS * NSLICE * 256 * 4, stream);
    if (n < MPAD) {
        hipMemsetAsync(u + (size_t)n * UDIM, 0, (size_t)(MPAD - n) * UDIM * 2, stream);
    }

    // weight precompute
    k_prep_v<<<(LAYERS * HIDD * 512 + 255) / 256, 256, 0, stream>>>(Wl, Vb);
    k_prep_a<<<(LAYERS * HEADS * HIDD + 255) / 256, 256, 0, stream>>>(Wl, a_src, a_dst, ws, wd);
    k_prep_wc<<<(HIDD * UDIM + 255) / 256, 256, 0, stream>>>(Wc, Wcb);

    // CSR build
    k_deg<<<(tot + 255) / 256, 256, 0, stream>>>(ei, deg, E, tot);
    k_scan1<<<NB, 256, 0, stream>>>(deg, rowptr, partials, n);
    k_scan2<<<1, 256, 0, stream>>>(partials, NB);
    k_scan3<<<NB, 256, 0, stream>>>(deg, partials, rowptr, cursor, n);
    k_scatter<<<(tot + 255) / 256, 256, 0, stream>>>(ei, cursor, csr_src, E, tot);

    // encoder
    k_enc<<<(n * EMBD + 255) / 256, 256, 0, stream>>>(x, emb, Wf, bf, u, n);
    k_gemm_enc<<<MPAD / 128, 256, 0, stream>>>(u, Wcb, bc, h, hb, n);
    k_al0<<<(n + 3) / 4, 256, 0, stream>>>(h, ws, wd, al_s, al_d, n);

    float invn = 1.0f / (float)n;
    int NLB = (n + 15) / 16;
    for (int l = 0; l < LAYERS; l++) {
        k_layer<<<NLB, 1024, 0, stream>>>(rowptr, csr_src, al_s, al_d, hb,
                                          Vb + (size_t)l * HIDD * 512, agg,
                                          bnsums + (size_t)l * NSLICE * 256, n);
        k_bnfin<<<1, 128, 0, stream>>>(bnsums + (size_t)l * NSLICE * 256, gamma + l * HIDD,
                                       beta + l * HIDD, scale, shift, invn);
        if (l < LAYERS - 1)
            k_apply<0><<<(n + 3) / 4, 256, 0, stream>>>(
                agg, scale, shift, h, hb,
                ws + (size_t)(l + 1) * 512, wd + (size_t)(l + 1) * 512, al_s, al_d,
                nullptr, nullptr, nullptr, n);
        else
            k_apply<1><<<(n + 3) / 4, 256, 0, stream>>>(
                agg, scale, shift, h, hb,
                nullptr, nullptr, nullptr, nullptr, Wout, bout, out, n);
    }
}

// Round 14
// 457.398 us; speedup vs baseline: 2.2206x; 1.1428x over previous
//
#include <hip/hip_runtime.h>
#include <hip/hip_bf16.h>
#include <math.h>

#define INDIM 16
#define EMBD 32
#define UDIM 64
#define HIDD 128
#define HEADS 4
#define LAYERS 3
#define MPAD 50048  // 391 * 128
#define NSLICE 32   // bn-sum stripes (atomic contention reduction)

typedef short v8s __attribute__((ext_vector_type(8)));
typedef float v4f __attribute__((ext_vector_type(4)));

__device__ __forceinline__ float lrelu(float x) { return x > 0.f ? x : 0.2f * x; }
__device__ __forceinline__ float bf2f(unsigned int bits16) {
    unsigned int u = bits16 << 16;
    return __builtin_bit_cast(float, u);
}
__device__ __forceinline__ unsigned short f2bf(float f) {
    unsigned int u = __builtin_bit_cast(unsigned int, f);
    unsigned int lsb = (u >> 16) & 1;
    u += 0x7fff + lsb;  // round to nearest even
    return (unsigned short)(u >> 16);
}

// ---------------- encoder features: u = [emb, x@Wf^T + bf] in bf16 ----------------
__global__ __launch_bounds__(256) void k_enc(const float* __restrict__ x,
                                             const float* __restrict__ emb,
                                             const float* __restrict__ Wf,
                                             const float* __restrict__ bf,
                                             unsigned short* __restrict__ u, int n) {
    int i = blockIdx.x * 256 + threadIdx.x;
    if (i >= n * EMBD) return;
    int node = i >> 5, j = i & 31;
    const float* xr = x + (size_t)node * INDIM;
    const float* wr = Wf + (size_t)j * INDIM;
    float s = bf[j];
#pragma unroll
    for (int k = 0; k < INDIM; k++) s += xr[k] * wr[k];
    u[(size_t)node * UDIM + EMBD + j] = f2bf(s);
    u[(size_t)node * UDIM + j] = f2bf(emb[(size_t)node * EMBD + j]);
}

// ---------------- fused weight precompute: Vb, ws/wd, Wcb in one launch ----------------
// idx < NV: Vb;  NV <= idx < NV+NA: ws/wd;  NV+NA <= idx < NV+NA+NW: Wcb.
__global__ __launch_bounds__(256) void k_prep(const float* __restrict__ Wl,
                                              const float* __restrict__ a_s,
                                              const float* __restrict__ a_d,
                                              const float* __restrict__ Wc,
                                              unsigned short* __restrict__ Vb,
                                              float* __restrict__ ws, float* __restrict__ wd,
                                              unsigned short* __restrict__ Wcb) {
    const int NV = LAYERS * HIDD * 512;
    const int NA = LAYERS * HEADS * HIDD;
    int i = blockIdx.x * 256 + threadIdx.x;
    if (i < NV) {
        int l = i >> 16;
        int rem = i & 65535;
        int c = rem >> 9;
        int f = rem & 511;
        int h = f >> 7, k = f & 127;
        Vb[i] = f2bf(Wl[(size_t)l * 512 * HIDD + (size_t)(h * HIDD + c) * HIDD + k]);
    } else if (i < NV + NA) {
        int j = i - NV;
        int l = j >> 9, h = (j >> 7) & 3, k = j & 127;
        const float* W = Wl + (size_t)l * 512 * HIDD;
        const float* as = a_s + l * 512 + h * HIDD;
        const float* ad = a_d + l * 512 + h * HIDD;
        float ss = 0.f, sd = 0.f;
        for (int c = 0; c < HIDD; c++) {
            float w = W[(size_t)(h * HIDD + c) * HIDD + k];
            ss += as[c] * w;
            sd += ad[c] * w;
        }
        ws[j] = ss;
        wd[j] = sd;
    } else if (i < NV + NA + HIDD * UDIM) {
        int j = i - NV - NA;
        Wcb[j] = f2bf(Wc[j]);
    }
}

// ---------------- encoder MFMA GEMM: O(M,128) = A(M,64) @ B(128,64)^T + bias, relu ----------------
__global__ __launch_bounds__(256) void k_gemm_enc(const unsigned short* __restrict__ A,
                                                  const unsigned short* __restrict__ B,
                                                  const float* __restrict__ bias,
                                                  float* __restrict__ O,
                                                  unsigned short* __restrict__ Ob, int M) {
    const int K = UDIM;
    int tid = threadIdx.x;
    int lane = tid & 63, wid = tid >> 6;
    int wm = wid >> 1, wn = wid & 1;
    int bm = blockIdx.x * 128;
    int lr = lane & 15, lk = lane >> 4;
    v4f acc[4][4] = {};
    const unsigned short* Abase = A + (size_t)(bm + wm * 64 + lr) * K + lk * 8;
    const unsigned short* Bbase = B + (size_t)(wn * 64 + lr) * K + lk * 8;
#pragma unroll
    for (int kk = 0; kk < K / 32; kk++) {
        v8s a[4], b[4];
#pragma unroll
        for (int f = 0; f < 4; f++) {
            a[f] = *(const v8s*)(Abase + (size_t)(f * 16) * K + kk * 32);
            b[f] = *(const v8s*)(Bbase + (size_t)(f * 16) * K + kk * 32);
        }
#pragma unroll
        for (int i = 0; i < 4; i++)
#pragma unroll
            for (int j = 0; j < 4; j++)
                acc[i][j] = __builtin_amdgcn_mfma_f32_16x16x32_bf16(a[i], b[j], acc[i][j], 0, 0, 0);
    }
#pragma unroll
    for (int i = 0; i < 4; i++) {
#pragma unroll
        for (int r = 0; r < 4; r++) {
            int row = bm + wm * 64 + i * 16 + lk * 4 + r;
            if (row >= M) continue;
#pragma unroll
            for (int j = 0; j < 4; j++) {
                int col = wn * 64 + j * 16 + lr;
                float v = fmaxf(acc[i][j][r] + bias[col], 0.f);
                O[(size_t)row * HIDD + col] = v;
                Ob[(size_t)row * HIDD + col] = f2bf(v);
            }
        }
    }
}

// ---------------- CSR build ----------------
__global__ __launch_bounds__(256) void k_deg(const int* __restrict__ ei, int* __restrict__ deg,
                                             int E, int tot) {
    int e = blockIdx.x * 256 + threadIdx.x;
    if (e >= tot) return;
    int dst = (e < E) ? ei[E + e] : (e - E);
    atomicAdd(&deg[dst], 1);
}

__global__ __launch_bounds__(256) void k_scan1(const int* __restrict__ deg,
                                               int* __restrict__ rowptr,
                                               int* __restrict__ partials, int n) {
    int tid = threadIdx.x;
    int i = blockIdx.x * 256 + tid;
    int v = (i < n) ? deg[i] : 0;
    __shared__ int sm[256];
    sm[tid] = v;
    __syncthreads();
    for (int off = 1; off < 256; off <<= 1) {
        int t = (tid >= off) ? sm[tid - off] : 0;
        __syncthreads();
        sm[tid] += t;
        __syncthreads();
    }
    if (i < n) rowptr[i] = sm[tid] - v;  // exclusive within block
    if (tid == 255) partials[blockIdx.x] = sm[255];
}

__global__ __launch_bounds__(256) void k_scan2(int* __restrict__ partials, int nb) {
    int tid = threadIdx.x;
    int v = (tid < nb) ? partials[tid] : 0;
    __shared__ int sm[256];
    sm[tid] = v;
    __syncthreads();
    for (int off = 1; off < 256; off <<= 1) {
        int t = (tid >= off) ? sm[tid - off] : 0;
        __syncthreads();
        sm[tid] += t;
        __syncthreads();
    }
    if (tid < nb) partials[tid] = sm[tid] - v;  // exclusive
}

__global__ __launch_bounds__(256) void k_scan3(const int* __restrict__ deg,
                                               const int* __restrict__ partials,
                                               int* __restrict__ rowptr,
                                               int* __restrict__ cursor, int n) {
    int i = blockIdx.x * 256 + threadIdx.x;
    if (i >= n) return;
    int r = rowptr[i] + partials[blockIdx.x];
    rowptr[i] = r;
    cursor[i] = r;
    if (i == n - 1) rowptr[n] = r + deg[i];
}

__global__ __launch_bounds__(256) void k_scatter(const int* __restrict__ ei, int* __restrict__ cursor,
                                                 int* __restrict__ csr_src, int E, int tot) {
    int e = blockIdx.x * 256 + threadIdx.x;
    if (e >= tot) return;
    int src = (e < E) ? ei[e] : (e - E);
    int dst = (e < E) ? ei[E + e] : (e - E);
    int pos = atomicAdd(&cursor[dst], 1);
    csr_src[pos] = src;
}

// ---------------- layer-0 attention logits from fp32 h ----------------
__global__ __launch_bounds__(256) void k_al0(const float* __restrict__ h,
                                             const float* __restrict__ ws,
                                             const float* __restrict__ wd,
                                             float* __restrict__ al_s, float* __restrict__ al_d,
                                             int n) {
    int wid = threadIdx.x >> 6, lane = threadIdx.x & 63;
    int node = blockIdx.x * 4 + wid;
    if (node >= n) return;
    float2 v = *(const float2*)(h + (size_t)node * HIDD + 2 * lane);
    float s[8];
#pragma unroll
    for (int hh = 0; hh < 4; hh++) {
        float2 w1 = *(const float2*)(ws + hh * HIDD + 2 * lane);
        float2 w2 = *(const float2*)(wd + hh * HIDD + 2 * lane);
        s[hh] = v.x * w1.x + v.y * w1.y;
        s[4 + hh] = v.x * w2.x + v.y * w2.y;
    }
#pragma unroll
    for (int o = 32; o; o >>= 1)
#pragma unroll
        for (int q = 0; q < 8; q++) s[q] += __shfl_xor(s[q], o);
    if (lane == 0) {
        *(float4*)(al_s + (size_t)node * 4) = make_float4(s[0], s[1], s[2], s[3]);
        *(float4*)(al_d + (size_t)node * 4) = make_float4(s[4], s[5], s[6], s[7]);
    }
}

// ---------------- fused layer: softmax + prefetch-pipelined gather + MFMA + BN stats -------
// Gather: 4-slot granularity, but next iteration's 4 row loads are issued BEFORE the current
// FMAs (8 loads in flight, no extra padding). Phase B = R9 structure (LDS s1/s2 + stripes).
__global__ __launch_bounds__(1024) void k_layer(const int* __restrict__ rowptr,
                                                const int* __restrict__ csr_src,
                                                const float* __restrict__ al_s,
                                                const float* __restrict__ al_d,
                                                const unsigned short* __restrict__ hb,
                                                const unsigned short* __restrict__ Vb,
                                                unsigned short* __restrict__ aggb,
                                                float* __restrict__ bns, int n) {
    __shared__ unsigned int Gw[16 * 256];
    __shared__ float s1[128], s2[128];
    __shared__ int Ssrc[16][64];
    __shared__ float Sal[16][4][64];
    int tid = threadIdx.x, lane = tid & 63, w = tid >> 6;
    if (tid < 128) { s1[tid] = 0.f; s2[tid] = 0.f; }
    int node0 = blockIdx.x * 16;
    int node = node0 + w;
    const float4* als4 = (const float4*)al_s;
    const unsigned int* h2 = (const unsigned int*)hb;
    int sw = (w & 7) << 2;

    if (node < n) {
        int start = rowptr[node], end = rowptr[node + 1];
        int deg = end - start;
        float4 ad = ((const float4*)al_d)[node];
        if (deg <= 64) {
            // ---- softmax: lane = edge ----
            bool act = lane < deg;
            int src_l = act ? csr_src[start + lane] : 0;
            float e0 = -3.0e38f, e1 = -3.0e38f, e2 = -3.0e38f, e3 = -3.0e38f;
            if (act) {
                float4 as = als4[src_l];
                e0 = lrelu(as.x + ad.x);
                e1 = lrelu(as.y + ad.y);
                e2 = lrelu(as.z + ad.z);
                e3 = lrelu(as.w + ad.w);
            }
            int span = 1;
            while (span < deg) span <<= 1;
            float m0 = e0, m1 = e1, m2 = e2, m3 = e3;
            for (int o = 1; o < span; o <<= 1) {
                m0 = fmaxf(m0, __shfl_xor(m0, o));
                m1 = fmaxf(m1, __shfl_xor(m1, o));
                m2 = fmaxf(m2, __shfl_xor(m2, o));
                m3 = fmaxf(m3, __shfl_xor(m3, o));
            }
            float p0 = act ? expf(e0 - m0) : 0.f;
            float p1 = act ? expf(e1 - m1) : 0.f;
            float p2 = act ? expf(e2 - m2) : 0.f;
            float p3 = act ? expf(e3 - m3) : 0.f;
            float t0 = p0, t1 = p1, t2 = p2, t3 = p3;
            for (int o = 1; o < span; o <<= 1) {
                t0 += __shfl_xor(t0, o);
                t1 += __shfl_xor(t1, o);
                t2 += __shfl_xor(t2, o);
                t3 += __shfl_xor(t3, o);
            }
            // stage src + alpha to wave-private LDS (inactive lanes: src=0, alpha=0)
            Ssrc[w][lane] = src_l;
            Sal[w][0][lane] = p0 / (t0 + 1e-16f);
            Sal[w][1][lane] = p1 / (t1 + 1e-16f);
            Sal[w][2][lane] = p2 / (t2 + 1e-16f);
            Sal[w][3][lane] = p3 / (t3 + 1e-16f);

            // ---- prefetch-pipelined gather: 4 slots/iter, next loads issued before FMAs ----
            float2 acc2[4] = {};
            int4 sC = *(const int4*)&Ssrc[w][0];
            unsigned int c0 = h2[(size_t)sC.x * 64 + lane];
            unsigned int c1 = h2[(size_t)sC.y * 64 + lane];
            unsigned int c2 = h2[(size_t)sC.z * 64 + lane];
            unsigned int c3 = h2[(size_t)sC.w * 64 + lane];
            for (int j0 = 0; j0 < deg; j0 += 4) {
                unsigned int n0 = 0, n1 = 0, n2 = 0, n3 = 0;
                int jn = j0 + 4;
                if (jn < deg) {
                    int4 sN = *(const int4*)&Ssrc[w][jn];
                    n0 = h2[(size_t)sN.x * 64 + lane];
                    n1 = h2[(size_t)sN.y * 64 + lane];
                    n2 = h2[(size_t)sN.z * 64 + lane];
                    n3 = h2[(size_t)sN.w * 64 + lane];
                }
                float4 a0 = *(const float4*)&Sal[w][0][j0];
                float4 a1 = *(const float4*)&Sal[w][1][j0];
                float4 a2 = *(const float4*)&Sal[w][2][j0];
                float4 a3 = *(const float4*)&Sal[w][3][j0];
#define EDGE_FMA(u, b0, b1, b2, b3)                                              \
    {                                                                            \
        float xlo = __builtin_bit_cast(float, (u) << 16);                        \
        float xhi = __builtin_bit_cast(float, (u) & 0xffff0000u);                \
        acc2[0].x = fmaf(b0, xlo, acc2[0].x);                                    \
        acc2[0].y = fmaf(b0, xhi, acc2[0].y);                                    \
        acc2[1].x = fmaf(b1, xlo, acc2[1].x);                                    \
        acc2[1].y = fmaf(b1, xhi, acc2[1].y);                                    \
        acc2[2].x = fmaf(b2, xlo, acc2[2].x);                                    \
        acc2[2].y = fmaf(b2, xhi, acc2[2].y);                                    \
        acc2[3].x = fmaf(b3, xlo, acc2[3].x);                                    \
        acc2[3].y = fmaf(b3, xhi, acc2[3].y);                                    \
    }
                EDGE_FMA(c0, a0.x, a1.x, a2.x, a3.x)
                EDGE_FMA(c1, a0.y, a1.y, a2.y, a3.y)
                EDGE_FMA(c2, a0.z, a1.z, a2.z, a3.z)
                EDGE_FMA(c3, a0.w, a1.w, a2.w, a3.w)
#undef EDGE_FMA
                c0 = n0; c1 = n1; c2 = n2; c3 = n3;
            }
#pragma unroll
            for (int hh = 0; hh < 4; hh++) {
                unsigned int p = (unsigned int)f2bf(acc2[hh].x) |
                                 ((unsigned int)f2bf(acc2[hh].y) << 16);
                Gw[w * 256 + ((hh * 64 + lane) ^ sw)] = p;
            }
        } else {
            // ---- rare fallback: serial-broadcast gather ----
            float m0 = -3.0e38f, m1 = -3.0e38f, m2 = -3.0e38f, m3 = -3.0e38f;
            for (int j = start + lane; j < end; j += 64) {
                float4 as = als4[csr_src[j]];
                m0 = fmaxf(m0, lrelu(as.x + ad.x));
                m1 = fmaxf(m1, lrelu(as.y + ad.y));
                m2 = fmaxf(m2, lrelu(as.z + ad.z));
                m3 = fmaxf(m3, lrelu(as.w + ad.w));
            }
#pragma unroll
            for (int o = 32; o; o >>= 1) {
                m0 = fmaxf(m0, __shfl_xor(m0, o));
                m1 = fmaxf(m1, __shfl_xor(m1, o));
                m2 = fmaxf(m2, __shfl_xor(m2, o));
                m3 = fmaxf(m3, __shfl_xor(m3, o));
            }
            float t0 = 0.f, t1 = 0.f, t2 = 0.f, t3 = 0.f;
            for (int j = start + lane; j < end; j += 64) {
                float4 as = als4[csr_src[j]];
                t0 += expf(lrelu(as.x + ad.x) - m0);
                t1 += expf(lrelu(as.y + ad.y) - m1);
                t2 += expf(lrelu(as.z + ad.z) - m2);
                t3 += expf(lrelu(as.w + ad.w) - m3);
            }
#pragma unroll
            for (int o = 32; o; o >>= 1) {
                t0 += __shfl_xor(t0, o);
                t1 += __shfl_xor(t1, o);
                t2 += __shfl_xor(t2, o);
                t3 += __shfl_xor(t3, o);
            }
            float i0 = 1.f / (t0 + 1e-16f), i1 = 1.f / (t1 + 1e-16f);
            float i2 = 1.f / (t2 + 1e-16f), i3 = 1.f / (t3 + 1e-16f);
            float acc[4][2] = {};
            for (int base = start; base < end; base += 64) {
                int cnt = min(64, end - base);
                bool act2 = lane < cnt;
                int src_l = act2 ? csr_src[base + lane] : 0;
                float a0 = 0.f, a1 = 0.f, a2 = 0.f, a3 = 0.f;
                if (act2) {
                    float4 as = als4[src_l];
                    a0 = expf(lrelu(as.x + ad.x) - m0) * i0;
                    a1 = expf(lrelu(as.y + ad.y) - m1) * i1;
                    a2 = expf(lrelu(as.z + ad.z) - m2) * i2;
                    a3 = expf(lrelu(as.w + ad.w) - m3) * i3;
                }
                for (int jj = 0; jj < cnt; jj++) {
                    int sj = __shfl(src_l, jj);
                    float b0 = __shfl(a0, jj), b1 = __shfl(a1, jj);
                    float b2 = __shfl(a2, jj), b3 = __shfl(a3, jj);
                    unsigned int uu = h2[(size_t)sj * 64 + lane];
                    float x0 = bf2f(uu & 0xffff), x1 = bf2f(uu >> 16);
                    acc[0][0] += b0 * x0; acc[0][1] += b0 * x1;
                    acc[1][0] += b1 * x0; acc[1][1] += b1 * x1;
                    acc[2][0] += b2 * x0; acc[2][1] += b2 * x1;
                    acc[3][0] += b3 * x0; acc[3][1] += b3 * x1;
                }
            }
#pragma unroll
            for (int hh = 0; hh < 4; hh++) {
                unsigned int p = (unsigned int)f2bf(acc[hh][0]) |
                                 ((unsigned int)f2bf(acc[hh][1]) << 16);
                Gw[w * 256 + ((hh * 64 + lane) ^ sw)] = p;
            }
        }
    } else {
        // pad rows: zero
#pragma unroll
        for (int hh = 0; hh < 4; hh++) Gw[w * 256 + ((hh * 64 + lane) ^ sw)] = 0;
    }
    __syncthreads();

    // ---- Phase B: agg(16x128) = G(16x512) @ Vb(128x512)^T; wave w<8 -> cols [w*16, w*16+16)
    if (w < 8) {
        int lr = lane & 15, lk = lane >> 4;
        int swr = (lr & 7) << 2;
        v4f a2 = {};
        const unsigned short* Bb = Vb + (size_t)(w * 16 + lr) * 512 + lk * 8;
#pragma unroll
        for (int kk = 0; kk < 16; kk++) {
            v8s a = *(const v8s*)(&Gw[lr * 256 + ((kk * 16 + lk * 4) ^ swr)]);
            v8s b = *(const v8s*)(Bb + kk * 32);
            a2 = __builtin_amdgcn_mfma_f32_16x16x32_bf16(a, b, a2, 0, 0, 0);
        }
        int col = w * 16 + lr;
        float ls = 0.f, lq = 0.f;
#pragma unroll
        for (int r = 0; r < 4; r++) {
            int nd = node0 + lk * 4 + r;
            float v = a2[r];
            if (nd < n) {
                aggb[(size_t)nd * HIDD + col] = f2bf(v);
                ls += v;
                lq += v * v;
            }
        }
        atomicAdd(&s1[col], ls);
        atomicAdd(&s2[col], lq);
    }
    __syncthreads();
    if (tid < 128) {
        float* slice = bns + (size_t)(blockIdx.x & (NSLICE - 1)) * 256;
        atomicAdd(&slice[tid], s1[tid]);
        atomicAdd(&slice[128 + tid], s2[tid]);
    }
}

// ---------------- BN finalize: reduce NSLICE stripes -> scale/shift (1 block) ----------------
__global__ __launch_bounds__(128) void k_bnfin(const float* __restrict__ bns,
                                               const float* __restrict__ gamma,
                                               const float* __restrict__ beta,
                                               float* __restrict__ scale,
                                               float* __restrict__ shift, float invn) {
    int c = threadIdx.x;
    float s = 0.f, q = 0.f;
    for (int sl = 0; sl < NSLICE; sl++) {
        s += bns[sl * 256 + c];
        q += bns[sl * 256 + 128 + c];
    }
    float mu = s * invn;
    float var = q * invn - mu * mu;
    float sc = gamma[c] * rsqrtf(0.0625f * var + 1e-5f) * 0.25f;  // 0.25 head-mean folded
    scale[c] = sc;
    shift[c] = beta[c] - mu * sc;
}

// ---------------- fused BN apply + residual + (next-layer al | output head) ----------------
template <int MODE>
__global__ __launch_bounds__(256) void k_apply(const unsigned short* __restrict__ aggb,
                                               const float* __restrict__ scale,
                                               const float* __restrict__ shift,
                                               float* __restrict__ h,
                                               unsigned short* __restrict__ hb,
                                               const float* __restrict__ ws,
                                               const float* __restrict__ wd,
                                               float* __restrict__ al_s,
                                               float* __restrict__ al_d,
                                               const float* __restrict__ Wout,
                                               const float* __restrict__ bout,
                                               float* __restrict__ out, int n) {
    int wid = threadIdx.x >> 6, lane = threadIdx.x & 63;
    int node = blockIdx.x * 4 + wid;
    if (node >= n) return;
    int c0 = 2 * lane, c1 = 2 * lane + 1;
    unsigned int ag2 = ((const unsigned int*)aggb)[(size_t)node * 64 + lane];
    float agx = bf2f(ag2 & 0xffff), agy = bf2f(ag2 >> 16);
    float2 ho = *(const float2*)(h + (size_t)node * HIDD + c0);
    float v0 = fmaxf(agx * scale[c0] + shift[c0], 0.f) + ho.x;
    float v1 = fmaxf(agy * scale[c1] + shift[c1], 0.f) + ho.y;
    if (MODE == 0) {
        *(float2*)(h + (size_t)node * HIDD + c0) = make_float2(v0, v1);
        ((unsigned int*)hb)[(size_t)node * 64 + lane] =
            (unsigned int)f2bf(v0) | ((unsigned int)f2bf(v1) << 16);
        float s[8];
#pragma unroll
        for (int hh = 0; hh < 4; hh++) {
            float2 w1 = *(const float2*)(ws + hh * HIDD + c0);
            float2 w2 = *(const float2*)(wd + hh * HIDD + c0);
            s[hh] = v0 * w1.x + v1 * w1.y;
            s[4 + hh] = v0 * w2.x + v1 * w2.y;
        }
#pragma unroll
        for (int o = 32; o; o >>= 1)
#pragma unroll
            for (int q = 0; q < 8; q++) s[q] += __shfl_xor(s[q], o);
        if (lane == 0) {
            *(float4*)(al_s + (size_t)node * 4) = make_float4(s[0], s[1], s[2], s[3]);
            *(float4*)(al_d + (size_t)node * 4) = make_float4(s[4], s[5], s[6], s[7]);
        }
    } else {
        float2 w = *(const float2*)(Wout + c0);
        float p = v0 * w.x + v1 * w.y;
#pragma unroll
        for (int o = 32; o; o >>= 1) p += __shfl_xor(p, o);
        if (lane == 0) {
            float v = p + bout[0];
            out[node] = fminf(fmaxf(v, -10.f), 10.f);
        }
    }
}

extern "C" void kernel_launch(void* const* d_in, const int* in_sizes, int n_in,
                              void* d_out, int out_size, void* d_ws, size_t ws_size,
                              hipStream_t stream) {
    const float* x = (const float*)d_in[0];
    const int* ei = (const int*)d_in[1];
    const float* emb = (const float*)d_in[2];
    const float* Wf = (const float*)d_in[3];
    const float* bf = (const float*)d_in[4];
    const float* Wc = (const float*)d_in[5];
    const float* bc = (const float*)d_in[6];
    const float* Wl = (const float*)d_in[7];
    const float* a_src = (const float*)d_in[8];
    const float* a_dst = (const float*)d_in[9];
    // d_in[10] = bl : cancels in BN mean subtraction
    const float* gamma = (const float*)d_in[11];
    const float* beta = (const float*)d_in[12];
    const float* Wout = (const float*)d_in[13];
    const float* bout = (const float*)d_in[14];
    float* out = (float*)d_out;

    int n = in_sizes[0] / INDIM;  // 50000
    int E = in_sizes[1] / 2;      // 400000
    int tot = E + n;
    int NB = (n + 255) / 256;  // scan blocks

    size_t off = 0;
    auto alloc = [&](size_t bytes) {
        void* p = (char*)d_ws + off;
        off = (off + bytes + 255) & ~(size_t)255;
        return p;
    };
    unsigned short* u = (unsigned short*)alloc((size_t)MPAD * UDIM * 2);
    float* h = (float*)alloc((size_t)MPAD * HIDD * 4);
    unsigned short* hb = (unsigned short*)alloc((size_t)MPAD * HIDD * 2);
    unsigned short* aggb = (unsigned short*)alloc((size_t)MPAD * HIDD * 2);
    float* al_s = (float*)alloc((size_t)n * HEADS * 4);
    float* al_d = (float*)alloc((size_t)n * HEADS * 4);
    // deg + bnsums adjacent -> single memset
    int* deg = (int*)alloc((size_t)n * 4);
    float* bnsums = (float*)alloc((size_t)LAYERS * NSLICE * 256 * 4);
    int* rowptr = (int*)alloc(((size_t)n + 1) * 4);
    int* cursor = (int*)alloc((size_t)n * 4);
    int* csr_src = (int*)alloc((size_t)tot * 4);
    int* partials = (int*)alloc((size_t)NB * 4);
    unsigned short* Vb = (unsigned short*)alloc((size_t)LAYERS * HIDD * 512 * 2);
    unsigned short* Wcb = (unsigned short*)alloc((size_t)HIDD * UDIM * 2);
    float* ws = (float*)alloc((size_t)LAYERS * HEADS * HIDD * 4);
    float* wd = (float*)alloc((size_t)LAYERS * HEADS * HIDD * 4);
    float* scale = (float*)alloc(128 * 4);
    float* shift = (float*)alloc(128 * 4);
    (void)ws_size;

    hipMemsetAsync(deg, 0, (char*)(bnsums + LAYERS * NSLICE * 256) - (char*)deg, stream);
    if (n < MPAD) {
        hipMemsetAsync(u + (size_t)n * UDIM, 0, (size_t)(MPAD - n) * UDIM * 2, stream);
    }

    // fused weight precompute
    {
        int total = LAYERS * HIDD * 512 + LAYERS * HEADS * HIDD + HIDD * UDIM;
        k_prep<<<(total + 255) / 256, 256, 0, stream>>>(Wl, a_src, a_dst, Wc, Vb, ws, wd, Wcb);
    }

    // CSR build
    k_deg<<<(tot + 255) / 256, 256, 0, stream>>>(ei, deg, E, tot);
    k_scan1<<<NB, 256, 0, stream>>>(deg, rowptr, partials, n);
    k_scan2<<<1, 256, 0, stream>>>(partials, NB);
    k_scan3<<<NB, 256, 0, stream>>>(deg, partials, rowptr, cursor, n);
    k_scatter<<<(tot + 255) / 256, 256, 0, stream>>>(ei, cursor, csr_src, E, tot);

    // encoder
    k_enc<<<(n * EMBD + 255) / 256, 256, 0, stream>>>(x, emb, Wf, bf, u, n);
    k_gemm_enc<<<MPAD / 128, 256, 0, stream>>>(u, Wcb, bc, h, hb, n);
    k_al0<<<(n + 3) / 4, 256, 0, stream>>>(h, ws, wd, al_s, al_d, n);

    float invn = 1.0f / (float)n;
    int NLB = (n + 15) / 16;
    for (int l = 0; l < LAYERS; l++) {
        k_layer<<<NLB, 1024, 0, stream>>>(rowptr, csr_src, al_s, al_d, hb,
                                          Vb + (size_t)l * HIDD * 512, aggb,
                                          bnsums + (size_t)l * NSLICE * 256, n);
        k_bnfin<<<1, 128, 0, stream>>>(bnsums + (size_t)l * NSLICE * 256, gamma + l * HIDD,
                                       beta + l * HIDD, scale, shift, invn);
        if (l < LAYERS - 1)
            k_apply<0><<<(n + 3) / 4, 256, 0, stream>>>(
                aggb, scale, shift, h, hb,
                ws + (size_t)(l + 1) * 512, wd + (size_t)(l + 1) * 512, al_s, al_d,
                nullptr, nullptr, nullptr, n);
        else
            k_apply<1><<<(n + 3) / 4, 256, 0, stream>>>(
                aggb, scale, shift, h, hb,
                nullptr, nullptr, nullptr, nullptr, Wout, bout, out, n);
    }
}